// Round 2
// baseline (544.508 us; speedup 1.0000x reference)
//
#include <hip/hip_runtime.h>
#include <hip/hip_bf16.h>
#include <cstddef>

// Bn=256, N=197, C=192, H=3, hd=64, E=1024, hid=768, M = Bn*N = 50432 = 394*128
//
// ws layout (bytes):
//   [0,          38731776)   : aggF f32 [256][197][192]  -- later overlaid by h1 bf16 [50432][768]
//   [77463552,  116195328)   : qk  bf16 [50432][384]   (Q cols 0..191, K cols 192..383)
//   [116195328, 135561216)   : xn  bf16 [50432][192]   (reused as x2n after proj)
//   [154927104, 174587904)   : vt  bf16 [256][3][64][200]  (V transposed, t contiguous; cols 197..199 garbage)
//   [174587904, 175472640)   : bf16 weights (qkv, proj, fc1, fc2)
//   [175472640, 175473664)   : cnt int32[256]

typedef __attribute__((ext_vector_type(8))) short bf8_t;
typedef __attribute__((ext_vector_type(4))) float f4_t;

__device__ __forceinline__ float bf2f(unsigned short u) {
  union { unsigned int i; float f; } x; x.i = ((unsigned int)u) << 16; return x.f;
}
__device__ __forceinline__ unsigned short f2bf(float f) {
  unsigned int u = __builtin_bit_cast(unsigned int, f);
  u = (u + 0x7FFFu + ((u >> 16) & 1u)) >> 16;
  return (unsigned short)u;
}
// packed f32x2 -> bf16x2 (RTNE), single VALU op (no builtin on gfx950)
__device__ __forceinline__ unsigned int cvt_pk_bf16(float a, float b) {
  unsigned int r;
  asm("v_cvt_pk_bf16_f32 %0, %1, %2" : "=v"(r) : "v"(a), "v"(b));
  return r;
}
// DPP row_ror:<R> all-reduce step (rows of 16 lanes = one mfrag group), VALU pipe
template<int CTRL>
__device__ __forceinline__ float dpp_ror(float x) {
  return __builtin_bit_cast(float,
      __builtin_amdgcn_mov_dpp(__builtin_bit_cast(int, x), CTRL, 0xF, 0xF, false));
}

// ---------------------------------------------------------------------------
__global__ __launch_bounds__(256) void f2bf_kernel(const float* __restrict__ src,
                                                   unsigned short* __restrict__ dst, int n) {
  int i = blockIdx.x * 256 + threadIdx.x;
  if (i < n) dst[i] = f2bf(src[i]);
}

// ---------------------------------------------------------------------------
// per-dst edge count (single block)
// ---------------------------------------------------------------------------
__global__ __launch_bounds__(256) void cnt_kernel(const int* __restrict__ edge,
                                                  int* __restrict__ cntg) {
  __shared__ int c[256];
  int t = threadIdx.x;
  c[t] = 0;
  __syncthreads();
  for (int e = t; e < 1024; e += 256) atomicAdd(&c[edge[1024 + e]], 1);
  __syncthreads();
  cntg[t] = c[t];
}

// ---------------------------------------------------------------------------
// LayerNorm(fp32 in) -> bf16 out.  One wave per row (C=192, 3 elems/lane).
// ---------------------------------------------------------------------------
__global__ __launch_bounds__(256) void ln_bf16_kernel(const float* __restrict__ X,
    const float* __restrict__ g, const float* __restrict__ b,
    unsigned short* __restrict__ Y) {
  int row = blockIdx.x * 4 + (threadIdx.x >> 6);
  int lane = threadIdx.x & 63;
  const float* xr = X + (size_t)row * 192;
  float v0 = xr[lane], v1 = xr[lane + 64], v2 = xr[lane + 128];
  float s = v0 + v1 + v2, ss = v0 * v0 + v1 * v1 + v2 * v2;
#pragma unroll
  for (int o = 32; o > 0; o >>= 1) { s += __shfl_xor(s, o, 64); ss += __shfl_xor(ss, o, 64); }
  float mean = s * (1.f / 192.f);
  float var = ss * (1.f / 192.f) - mean * mean;
  float r = rsqrtf(var + 1e-5f);
  unsigned short* yr = Y + (size_t)row * 192;
  yr[lane]       = f2bf((v0 - mean) * r * g[lane]       + b[lane]);
  yr[lane + 64]  = f2bf((v1 - mean) * r * g[lane + 64]  + b[lane + 64]);
  yr[lane + 128] = f2bf((v2 - mean) * r * g[lane + 128] + b[lane + 128]);
}

// ---------------------------------------------------------------------------
// bf16 MFMA GEMM: C = f( A @ W^T ), tile 128x64, 4 waves.
// Grid: (ncols/64, nrows/128) -- n in blockIdx.x so consecutive blocks share
// the A row-panel (L2 locality).
// MODE 0: qkv -> qk bf16 (cols<384) + vt bf16 transposed (cols>=384)
// MODE 1: proj -> f32 (/cnt, +bias, +xres); AF32: A staged from f32 (aggF)
// MODE 2: fc1 -> bf16 gelu(+bias)
// MODE 3: fc2 -> f32 (+bias, +xres; in-place safe per-element)
// ---------------------------------------------------------------------------
template<int MODE, int NK, bool AF32 = false>
__global__ __launch_bounds__(256) void gemm_bf16(
    const unsigned short* __restrict__ A, const float* __restrict__ Af,
    const unsigned short* __restrict__ W,
    const float* __restrict__ bias, const float* __restrict__ xres,
    const int* __restrict__ cntg, void* __restrict__ Cout,
    unsigned short* __restrict__ Cvt, int ldc) {
  constexpr int LDA = 200;
  __shared__ unsigned short As[128 * LDA];
  __shared__ unsigned short Ws[64 * LDA];
  const int tid = threadIdx.x;
  const int m0 = blockIdx.y * 128, n0 = blockIdx.x * 64;
  const int wave = tid >> 6, lane = tid & 63;
  const int mfrag = lane & 15, quad = lane >> 4;
  const int K = NK * 192;

  f4_t acc[2][4];
#pragma unroll
  for (int i = 0; i < 2; ++i)
#pragma unroll
    for (int j = 0; j < 4; ++j) acc[i][j] = (f4_t){0.f, 0.f, 0.f, 0.f};

  for (int kc = 0; kc < NK; ++kc) {
    __syncthreads();
    if constexpr (AF32) {
#pragma unroll
      for (int it = 0; it < 24; ++it) {
        int idx = it * 256 + tid;
        int r = idx / 48, c = idx % 48;
        float4 t = *(const float4*)(Af + (size_t)(m0 + r) * K + kc * 192 + c * 4);
        unsigned int u0 = cvt_pk_bf16(t.x, t.y);
        unsigned int u1 = cvt_pk_bf16(t.z, t.w);
        uint2 p; p.x = u0; p.y = u1;
        *(uint2*)(As + r * LDA + c * 4) = p;
      }
    } else {
#pragma unroll
      for (int it = 0; it < 12; ++it) {
        int idx = it * 256 + tid;
        int r = idx / 24, c = idx % 24;
        *(float4*)(As + r * LDA + c * 8) =
            *(const float4*)(A + (size_t)(m0 + r) * K + kc * 192 + c * 8);
      }
    }
#pragma unroll
    for (int it = 0; it < 6; ++it) {
      int idx = it * 256 + tid;
      int r = idx / 24, c = idx % 24;
      *(float4*)(Ws + r * LDA + c * 8) =
          *(const float4*)(W + (size_t)(n0 + r) * K + kc * 192 + c * 8);
    }
    __syncthreads();
#pragma unroll
    for (int ks = 0; ks < 6; ++ks) {
      bf8_t a0 = *(const bf8_t*)(As + (wave * 32 + mfrag) * LDA + ks * 32 + quad * 8);
      bf8_t a1 = *(const bf8_t*)(As + (wave * 32 + 16 + mfrag) * LDA + ks * 32 + quad * 8);
#pragma unroll
      for (int nt = 0; nt < 4; ++nt) {
        bf8_t bf = *(const bf8_t*)(Ws + (nt * 16 + mfrag) * LDA + ks * 32 + quad * 8);
        acc[0][nt] = __builtin_amdgcn_mfma_f32_16x16x32_bf16(a0, bf, acc[0][nt], 0, 0, 0);
        acc[1][nt] = __builtin_amdgcn_mfma_f32_16x16x32_bf16(a1, bf, acc[1][nt], 0, 0, 0);
      }
    }
  }

#pragma unroll
  for (int mt = 0; mt < 2; ++mt)
#pragma unroll
    for (int nt = 0; nt < 4; ++nt)
#pragma unroll
      for (int reg = 0; reg < 4; ++reg) {
        int row = m0 + wave * 32 + mt * 16 + quad * 4 + reg;
        int col = n0 + nt * 16 + mfrag;
        float v = acc[mt][nt][reg];
        if constexpr (MODE == 0) {
          if (col < 384) {
            ((unsigned short*)Cout)[(size_t)row * 384 + col] = f2bf(v);
          } else {
            int cc = col - 384, hh = cc >> 6, dd = cc & 63;
            int bb = row / 197, tt = row - bb * 197;
            Cvt[((size_t)(bb * 3 + hh) * 64 + dd) * 200 + tt] = f2bf(v);
          }
        } else if constexpr (MODE == 1) {
          int c = cntg[row / 197];
          v = (c > 0) ? v / (float)c + bias[col] : 0.f;
          v += xres[(size_t)row * 192 + col];
          ((float*)Cout)[(size_t)row * ldc + col] = v;
        } else if constexpr (MODE == 2) {
          v += bias[col];
          v = 0.5f * v * (1.f + erff(v * 0.70710678118654752f));
          ((unsigned short*)Cout)[(size_t)row * ldc + col] = f2bf(v);
        } else {
          v += bias[col] + xres[(size_t)row * 192 + col];
          ((float*)Cout)[(size_t)row * ldc + col] = v;
        }
      }
}

// ---------------------------------------------------------------------------
// MFMA attention, one block per (edge e, head h).  q,v from dst; k from src.
// 512 threads / 8 waves.  K staged row-major from qk; V^T staged from
// pre-transposed vt.  S = Q@K^T, exact softmax in regs (DPP row_ror
// reductions on the VALU pipe -- the mfrag group is exactly one DPP row),
// P->LDS->PV.  Output o*inv accumulated directly into f32 agg via native
// f32 atomics (segment-sum commutes with the proj GEMM), eliminating the
// msgbuf round-trip and the aggregate kernel.
// ---------------------------------------------------------------------------
__global__ __launch_bounds__(512) void attnA_kernel(
    const unsigned short* __restrict__ qk, const unsigned short* __restrict__ vtg,
    const int* __restrict__ edge, float* __restrict__ aggF) {
  const int e = blockIdx.x, h = blockIdx.y;
  const int s = edge[e], b = edge[1024 + e];
  __shared__ unsigned short Ks[208 * 72];
  __shared__ unsigned short Vt[64 * 232];
  __shared__ unsigned short Ps[8][640];   // [wave][16*40], single buffer (DS in-order per wave)
  const int tid = threadIdx.x;
  const int wave = tid >> 6, lane = tid & 63;
  const int mfrag = lane & 15, quad = lane >> 4;

  // stage K rows (src s), coalesced 16B, conflict-free
  for (int i = tid; i < 197 * 8; i += 512) {
    int m = i >> 3, c8 = i & 7;
    *(float4*)(Ks + m * 72 + c8 * 8) =
        *(const float4*)(qk + (size_t)(s * 197 + m) * 384 + 192 + h * 64 + c8 * 8);
  }
  // stage V^T rows (dst b) from pre-transposed global, b128 conflict-free
  for (int i = tid; i < 64 * 25; i += 512) {
    int d = i / 25, c8 = i - d * 25;
    *(float4*)(Vt + d * 232 + c8 * 8) =
        *(const float4*)(vtg + ((size_t)(b * 3 + h) * 64 + d) * 200 + c8 * 8);
  }
  __syncthreads();
  // zero pad keys 197..231 (197..199 overwrite staged garbage)
  for (int i = tid; i < 64 * 35; i += 512) {
    int d = i / 35, kk = 197 + (i - d * 35);
    Vt[d * 232 + kk] = 0;
  }
  __syncthreads();

  for (int st = wave; st < 13; st += 8) {
    const int m0 = st * 16;
    const size_t qrow = (size_t)(b * 197 + min(m0 + mfrag, 196)) * 384 + h * 64;
    bf8_t a0 = *(const bf8_t*)(qk + qrow + quad * 8);
    bf8_t a1 = *(const bf8_t*)(qk + qrow + 32 + quad * 8);

    f4_t S[13];
#pragma unroll
    for (int nt = 0; nt < 13; ++nt) {
      bf8_t k0 = *(const bf8_t*)(Ks + (nt * 16 + mfrag) * 72 + quad * 8);
      bf8_t k1 = *(const bf8_t*)(Ks + (nt * 16 + mfrag) * 72 + 32 + quad * 8);
      f4_t z = (f4_t){0.f, 0.f, 0.f, 0.f};
      z = __builtin_amdgcn_mfma_f32_16x16x32_bf16(a0, k0, z, 0, 0, 0);
      S[nt] = __builtin_amdgcn_mfma_f32_16x16x32_bf16(a1, k1, z, 0, 0, 0);
    }

    // exact softmax over keys; lane holds S[q=quad*4+reg][key=nt*16+mfrag].
    // only nt=12 has invalid keys (192..207): mask those lanes once.
#pragma unroll
    for (int reg = 0; reg < 4; ++reg)
      S[12][reg] = (mfrag < 5) ? S[12][reg] : -1e30f;

    float mx[4] = {-1e30f, -1e30f, -1e30f, -1e30f};
#pragma unroll
    for (int nt = 0; nt < 13; ++nt)
#pragma unroll
      for (int reg = 0; reg < 4; ++reg) mx[reg] = fmaxf(mx[reg], S[nt][reg]);
    // 16-lane all-reduce via DPP row_ror (VALU pipe; mfrag group == DPP row)
#pragma unroll
    for (int reg = 0; reg < 4; ++reg) {
      mx[reg] = fmaxf(mx[reg], dpp_ror<0x121>(mx[reg]));
      mx[reg] = fmaxf(mx[reg], dpp_ror<0x122>(mx[reg]));
      mx[reg] = fmaxf(mx[reg], dpp_ror<0x124>(mx[reg]));
      mx[reg] = fmaxf(mx[reg], dpp_ror<0x128>(mx[reg]));
    }

    // p = exp(0.125*(s-m)) = exp2(0.18033688*(s-m)); masked entries -> 0
    constexpr float CEXP = 0.18033688011112042f;
    float sum[4] = {0.f, 0.f, 0.f, 0.f};
#pragma unroll
    for (int nt = 0; nt < 13; ++nt)
#pragma unroll
      for (int reg = 0; reg < 4; ++reg) {
        float p = exp2f((S[nt][reg] - mx[reg]) * CEXP);
        S[nt][reg] = p;
        sum[reg] += p;
      }
#pragma unroll
    for (int reg = 0; reg < 4; ++reg) {
      sum[reg] += dpp_ror<0x121>(sum[reg]);
      sum[reg] += dpp_ror<0x122>(sum[reg]);
      sum[reg] += dpp_ror<0x124>(sum[reg]);
      sum[reg] += dpp_ror<0x128>(sum[reg]);
    }
    float inv[4];
#pragma unroll
    for (int reg = 0; reg < 4; ++reg) inv[reg] = __builtin_amdgcn_rcpf(sum[reg]);

    // PV: chunked P->LDS (wave-private; DS in-order per wave makes the
    // single buffer safe).
    f4_t o[4];
#pragma unroll
    for (int dt = 0; dt < 4; ++dt) o[dt] = (f4_t){0.f, 0.f, 0.f, 0.f};
    unsigned short* buf = Ps[wave];
#pragma unroll
    for (int kt = 0; kt < 7; ++kt) {
#pragma unroll
      for (int reg = 0; reg < 4; ++reg) {
        float p0 = S[kt * 2][reg];
        float p1 = (kt * 2 + 1 < 13) ? S[kt * 2 + 1][reg] : 0.f;
        unsigned int u = cvt_pk_bf16(p0, p1);
        buf[(quad * 4 + reg) * 40 + mfrag]      = (unsigned short)u;
        buf[(quad * 4 + reg) * 40 + 16 + mfrag] = (unsigned short)(u >> 16);
      }
      bf8_t pf = *(const bf8_t*)(buf + mfrag * 40 + quad * 8);
#pragma unroll
      for (int dt = 0; dt < 4; ++dt) {
        bf8_t vf = *(const bf8_t*)(Vt + (dt * 16 + mfrag) * 232 + kt * 32 + quad * 8);
        o[dt] = __builtin_amdgcn_mfma_f32_16x16x32_bf16(pf, vf, o[dt], 0, 0, 0);
      }
    }

    // accumulate into f32 agg (native f32 atomic add; 16 consecutive lanes
    // hit 16 consecutive floats -> coalesced)
#pragma unroll
    for (int dt = 0; dt < 4; ++dt)
#pragma unroll
      for (int reg = 0; reg < 4; ++reg) {
        int q = m0 + quad * 4 + reg;
        if (q < 197)
          unsafeAtomicAdd(&aggF[((size_t)b * 197 + q) * 192 + h * 64 + dt * 16 + mfrag],
                          o[dt][reg] * inv[reg]);
      }
  }
}

// ---------------------------------------------------------------------------
extern "C" void kernel_launch(void* const* d_in, const int* in_sizes, int n_in,
                              void* d_out, int out_size, void* d_ws, size_t ws_size,
                              hipStream_t stream) {
  const float* x      = (const float*)d_in[0];
  const int*   edge   = (const int*)d_in[1];
  const float* n1g    = (const float*)d_in[2];
  const float* n1b    = (const float*)d_in[3];
  const float* qkv_w  = (const float*)d_in[4];
  const float* proj_w = (const float*)d_in[5];
  const float* proj_b = (const float*)d_in[6];
  const float* n2g    = (const float*)d_in[7];
  const float* n2b    = (const float*)d_in[8];
  const float* fc1_w  = (const float*)d_in[9];
  const float* fc1_b  = (const float*)d_in[10];
  const float* fc2_w  = (const float*)d_in[11];
  const float* fc2_b  = (const float*)d_in[12];
  float* out = (float*)d_out;

  char* ws = (char*)d_ws;
  float*          aggF   = (float*)ws;
  unsigned short* h1     = (unsigned short*)ws;                    // overlays aggF after proj
  unsigned short* qk     = (unsigned short*)(ws + 77463552);
  unsigned short* xn     = (unsigned short*)(ws + 116195328);
  unsigned short* vtg    = (unsigned short*)(ws + 154927104);
  unsigned short* wqkv   = (unsigned short*)(ws + 174587904);
  unsigned short* wproj  = (unsigned short*)(ws + 174809088);
  unsigned short* wfc1   = (unsigned short*)(ws + 174882816);
  unsigned short* wfc2   = (unsigned short*)(ws + 175177728);
  int*            cntg   = (int*)           (ws + 175472640);

  dim3 blk(256);
  hipMemsetAsync(aggF, 0, 38731776, stream);
  f2bf_kernel<<<dim3(432), blk, 0, stream>>>(qkv_w, wqkv, 110592);
  f2bf_kernel<<<dim3(144), blk, 0, stream>>>(proj_w, wproj, 36864);
  f2bf_kernel<<<dim3(576), blk, 0, stream>>>(fc1_w, wfc1, 147456);
  f2bf_kernel<<<dim3(576), blk, 0, stream>>>(fc2_w, wfc2, 147456);
  cnt_kernel<<<dim3(1), blk, 0, stream>>>(edge, cntg);

  ln_bf16_kernel<<<dim3(12608), blk, 0, stream>>>(x, n1g, n1b, xn);
  gemm_bf16<0, 1><<<dim3(9, 394), blk, 0, stream>>>(xn, nullptr, wqkv, nullptr, nullptr, nullptr, qk, vtg, 384);
  attnA_kernel<<<dim3(1024, 3), dim3(512), 0, stream>>>(qk, vtg, edge, aggF);
  gemm_bf16<1, 1, true><<<dim3(3, 394), blk, 0, stream>>>(nullptr, aggF, wproj, proj_b, x, cntg, out, nullptr, 192);
  ln_bf16_kernel<<<dim3(12608), blk, 0, stream>>>(out, n2g, n2b, xn);
  gemm_bf16<2, 1><<<dim3(12, 394), blk, 0, stream>>>(xn, nullptr, wfc1, fc1_b, nullptr, nullptr, h1, nullptr, 768);
  gemm_bf16<3, 4><<<dim3(3, 394), blk, 0, stream>>>(h1, nullptr, wfc2, fc2_b, out, nullptr, out, nullptr, 192);
}

// Round 3
// 510.860 us; speedup vs baseline: 1.0659x; 1.0659x over previous
//
#include <hip/hip_runtime.h>
#include <hip/hip_bf16.h>
#include <cstddef>

// Bn=256, N=197, C=192, H=3, hd=64, E=1024, hid=768, M = Bn*N = 50432 = 394*128
//
// ws layout (bytes):
//   [0,          77463552)   : msgbuf bf16 [1024][197][192]  -- later overlaid by h1 bf16 [50432][768]
//   [77463552,  116195328)   : qk  bf16 [50432][384]   (Q cols 0..191, K cols 192..383)
//   [116195328, 135561216)   : xn  bf16 [50432][192]   (reused as x2n after proj)
//   [135561216, 154927104)   : agg bf16 [50432][192]
//   [154927104, 174587904)   : vt  bf16 [256][3][64][200]  (V transposed, key-permuted within
//                               32-token chunks 0..5: pos = c*32 + 2*(w&15) + (w>>4); chunk 6 identity)
//   [174587904, 175472640)   : bf16 weights (qkv, proj, fc1, fc2)
//   [175472640, 175473664)   : cnt int32[256]

typedef __attribute__((ext_vector_type(8))) short bf8_t;
typedef __attribute__((ext_vector_type(4))) float f4_t;

__device__ __forceinline__ float bf2f(unsigned short u) {
  union { unsigned int i; float f; } x; x.i = ((unsigned int)u) << 16; return x.f;
}
__device__ __forceinline__ unsigned short f2bf(float f) {
  unsigned int u = __builtin_bit_cast(unsigned int, f);
  u = (u + 0x7FFFu + ((u >> 16) & 1u)) >> 16;
  return (unsigned short)u;
}
// packed f32x2 -> bf16x2 (RTNE), single VALU op (no builtin on gfx950)
__device__ __forceinline__ unsigned int cvt_pk_bf16(float a, float b) {
  unsigned int r;
  asm("v_cvt_pk_bf16_f32 %0, %1, %2" : "=v"(r) : "v"(a), "v"(b));
  return r;
}
// DPP row_ror:<R> all-reduce step (rows of 16 lanes = one mfrag group), VALU pipe
template<int CTRL>
__device__ __forceinline__ float dpp_ror(float x) {
  return __builtin_bit_cast(float,
      __builtin_amdgcn_mov_dpp(__builtin_bit_cast(int, x), CTRL, 0xF, 0xF, false));
}

// ---------------------------------------------------------------------------
__global__ __launch_bounds__(256) void f2bf_kernel(const float* __restrict__ src,
                                                   unsigned short* __restrict__ dst, int n) {
  int i = blockIdx.x * 256 + threadIdx.x;
  if (i < n) dst[i] = f2bf(src[i]);
}

// ---------------------------------------------------------------------------
// LayerNorm(fp32 in) -> bf16 out.  One wave per row (C=192, 3 elems/lane).
// ---------------------------------------------------------------------------
__global__ __launch_bounds__(256) void ln_bf16_kernel(const float* __restrict__ X,
    const float* __restrict__ g, const float* __restrict__ b,
    unsigned short* __restrict__ Y) {
  int row = blockIdx.x * 4 + (threadIdx.x >> 6);
  int lane = threadIdx.x & 63;
  const float* xr = X + (size_t)row * 192;
  float v0 = xr[lane], v1 = xr[lane + 64], v2 = xr[lane + 128];
  float s = v0 + v1 + v2, ss = v0 * v0 + v1 * v1 + v2 * v2;
#pragma unroll
  for (int o = 32; o > 0; o >>= 1) { s += __shfl_xor(s, o, 64); ss += __shfl_xor(ss, o, 64); }
  float mean = s * (1.f / 192.f);
  float var = ss * (1.f / 192.f) - mean * mean;
  float r = rsqrtf(var + 1e-5f);
  unsigned short* yr = Y + (size_t)row * 192;
  yr[lane]       = f2bf((v0 - mean) * r * g[lane]       + b[lane]);
  yr[lane + 64]  = f2bf((v1 - mean) * r * g[lane + 64]  + b[lane + 64]);
  yr[lane + 128] = f2bf((v2 - mean) * r * g[lane + 128] + b[lane + 128]);
}

// ---------------------------------------------------------------------------
// bf16 MFMA GEMM: C = f( A @ W^T ), tile 128x64, 4 waves.
// Grid: (ncols/64, nrows/128) -- n in blockIdx.x so consecutive blocks share
// the A row-panel (L2 locality).
// MODE 0: qkv -> qk bf16 (cols<384) + vt bf16 transposed+key-permuted (cols>=384)
// MODE 1: proj -> f32 (/cnt, +bias, +xres)
// MODE 2: fc1 -> bf16 gelu(+bias)
// MODE 3: fc2 -> f32 (+bias, +xres; in-place safe per-element)
// ---------------------------------------------------------------------------
template<int MODE, int NK>
__global__ __launch_bounds__(256) void gemm_bf16(
    const unsigned short* __restrict__ A, const unsigned short* __restrict__ W,
    const float* __restrict__ bias, const float* __restrict__ xres,
    const int* __restrict__ cntg, void* __restrict__ Cout,
    unsigned short* __restrict__ Cvt, int ldc) {
  constexpr int LDA = 200;
  __shared__ unsigned short As[128 * LDA];
  __shared__ unsigned short Ws[64 * LDA];
  const int tid = threadIdx.x;
  const int m0 = blockIdx.y * 128, n0 = blockIdx.x * 64;
  const int wave = tid >> 6, lane = tid & 63;
  const int mfrag = lane & 15, quad = lane >> 4;
  const int K = NK * 192;

  f4_t acc[2][4];
#pragma unroll
  for (int i = 0; i < 2; ++i)
#pragma unroll
    for (int j = 0; j < 4; ++j) acc[i][j] = (f4_t){0.f, 0.f, 0.f, 0.f};

  for (int kc = 0; kc < NK; ++kc) {
    __syncthreads();
#pragma unroll
    for (int it = 0; it < 12; ++it) {
      int idx = it * 256 + tid;
      int r = idx / 24, c = idx % 24;
      *(float4*)(As + r * LDA + c * 8) =
          *(const float4*)(A + (size_t)(m0 + r) * K + kc * 192 + c * 8);
    }
#pragma unroll
    for (int it = 0; it < 6; ++it) {
      int idx = it * 256 + tid;
      int r = idx / 24, c = idx % 24;
      *(float4*)(Ws + r * LDA + c * 8) =
          *(const float4*)(W + (size_t)(n0 + r) * K + kc * 192 + c * 8);
    }
    __syncthreads();
#pragma unroll
    for (int ks = 0; ks < 6; ++ks) {
      bf8_t a0 = *(const bf8_t*)(As + (wave * 32 + mfrag) * LDA + ks * 32 + quad * 8);
      bf8_t a1 = *(const bf8_t*)(As + (wave * 32 + 16 + mfrag) * LDA + ks * 32 + quad * 8);
#pragma unroll
      for (int nt = 0; nt < 4; ++nt) {
        bf8_t bf = *(const bf8_t*)(Ws + (nt * 16 + mfrag) * LDA + ks * 32 + quad * 8);
        acc[0][nt] = __builtin_amdgcn_mfma_f32_16x16x32_bf16(a0, bf, acc[0][nt], 0, 0, 0);
        acc[1][nt] = __builtin_amdgcn_mfma_f32_16x16x32_bf16(a1, bf, acc[1][nt], 0, 0, 0);
      }
    }
  }

#pragma unroll
  for (int mt = 0; mt < 2; ++mt)
#pragma unroll
    for (int nt = 0; nt < 4; ++nt)
#pragma unroll
      for (int reg = 0; reg < 4; ++reg) {
        int row = m0 + wave * 32 + mt * 16 + quad * 4 + reg;
        int col = n0 + nt * 16 + mfrag;
        float v = acc[mt][nt][reg];
        if constexpr (MODE == 0) {
          if (col < 384) {
            ((unsigned short*)Cout)[(size_t)row * 384 + col] = f2bf(v);
          } else {
            int cc = col - 384, hh = cc >> 6, dd = cc & 63;
            int bb = row / 197, tt = row - bb * 197;
            // key permutation within 32-token chunks 0..5 (chunk 6 identity):
            // pos = c*32 + 2*(w&15) + (w>>4), so a lane's (k, k+16) pair is
            // adjacent in LDS for packed-u32 P writes in attn.
            int c5 = tt >> 5, w = tt & 31;
            int pos = (c5 < 6) ? c5 * 32 + 2 * (w & 15) + (w >> 4) : tt;
            Cvt[((size_t)(bb * 3 + hh) * 64 + dd) * 200 + pos] = f2bf(v);
          }
        } else if constexpr (MODE == 1) {
          int c = cntg[row / 197];
          v = (c > 0) ? v / (float)c + bias[col] : 0.f;
          v += xres[(size_t)row * 192 + col];
          ((float*)Cout)[(size_t)row * ldc + col] = v;
        } else if constexpr (MODE == 2) {
          v += bias[col];
          v = 0.5f * v * (1.f + erff(v * 0.70710678118654752f));
          ((unsigned short*)Cout)[(size_t)row * ldc + col] = f2bf(v);
        } else {
          v += bias[col] + xres[(size_t)row * 192 + col];
          ((float*)Cout)[(size_t)row * ldc + col] = v;
        }
      }
}

// ---------------------------------------------------------------------------
// MFMA attention, one block per (edge e, head h).  q,v from dst; k from src.
// 512 threads / 8 waves.  K staged row-major from qk; V^T staged from
// pre-transposed + key-permuted vt.  S = Q@K^T, exact softmax in regs (DPP
// row_ror reductions on the VALU pipe), P->LDS (packed u32 writes thanks to
// the key permutation; chunk 6 identity/split) -> PV -> msgbuf.
// ---------------------------------------------------------------------------
__global__ __launch_bounds__(512) void attnA_kernel(
    const unsigned short* __restrict__ qk, const unsigned short* __restrict__ vtg,
    const int* __restrict__ edge, unsigned short* __restrict__ msgbuf) {
  const int e = blockIdx.x, h = blockIdx.y;
  const int s = edge[e], b = edge[1024 + e];
  __shared__ unsigned short Ks[208 * 72];
  __shared__ unsigned short Vt[64 * 232];
  __shared__ unsigned short Ps[8][640];   // [wave][16*40], single buffer (DS in-order per wave)
  const int tid = threadIdx.x;
  const int wave = tid >> 6, lane = tid & 63;
  const int mfrag = lane & 15, quad = lane >> 4;

  // stage K rows (src s), coalesced 16B, conflict-free
  for (int i = tid; i < 197 * 8; i += 512) {
    int m = i >> 3, c8 = i & 7;
    *(float4*)(Ks + m * 72 + c8 * 8) =
        *(const float4*)(qk + (size_t)(s * 197 + m) * 384 + 192 + h * 64 + c8 * 8);
  }
  // stage V^T rows (dst b) from pre-transposed global, b128 conflict-free
  for (int i = tid; i < 64 * 25; i += 512) {
    int d = i / 25, c8 = i - d * 25;
    *(float4*)(Vt + d * 232 + c8 * 8) =
        *(const float4*)(vtg + ((size_t)(b * 3 + h) * 64 + d) * 200 + c8 * 8);
  }
  __syncthreads();
  // zero storage positions 197..231 (chunk 6 is identity-mapped, so garbage
  // tokens 197..199 sit at positions 197..199; 200..223 never staged)
  for (int i = tid; i < 64 * 35; i += 512) {
    int d = i / 35, kk = 197 + (i - d * 35);
    Vt[d * 232 + kk] = 0;
  }
  __syncthreads();

  for (int st = wave; st < 13; st += 8) {
    const int m0 = st * 16;
    const size_t qrow = (size_t)(b * 197 + min(m0 + mfrag, 196)) * 384 + h * 64;
    bf8_t a0 = *(const bf8_t*)(qk + qrow + quad * 8);
    bf8_t a1 = *(const bf8_t*)(qk + qrow + 32 + quad * 8);

    f4_t S[13];
#pragma unroll
    for (int nt = 0; nt < 13; ++nt) {
      bf8_t k0 = *(const bf8_t*)(Ks + (nt * 16 + mfrag) * 72 + quad * 8);
      bf8_t k1 = *(const bf8_t*)(Ks + (nt * 16 + mfrag) * 72 + 32 + quad * 8);
      f4_t z = (f4_t){0.f, 0.f, 0.f, 0.f};
      z = __builtin_amdgcn_mfma_f32_16x16x32_bf16(a0, k0, z, 0, 0, 0);
      S[nt] = __builtin_amdgcn_mfma_f32_16x16x32_bf16(a1, k1, z, 0, 0, 0);
    }

    // exact softmax over keys; lane holds S[q=quad*4+reg][key=nt*16+mfrag].
    // only nt=12 has invalid keys (192..207): mask those lanes once.
#pragma unroll
    for (int reg = 0; reg < 4; ++reg)
      S[12][reg] = (mfrag < 5) ? S[12][reg] : -1e30f;

    float mx[4] = {-1e30f, -1e30f, -1e30f, -1e30f};
#pragma unroll
    for (int nt = 0; nt < 13; ++nt)
#pragma unroll
      for (int reg = 0; reg < 4; ++reg) mx[reg] = fmaxf(mx[reg], S[nt][reg]);
    // 16-lane all-reduce via DPP row_ror (VALU pipe; mfrag group == DPP row)
#pragma unroll
    for (int reg = 0; reg < 4; ++reg) {
      mx[reg] = fmaxf(mx[reg], dpp_ror<0x121>(mx[reg]));
      mx[reg] = fmaxf(mx[reg], dpp_ror<0x122>(mx[reg]));
      mx[reg] = fmaxf(mx[reg], dpp_ror<0x124>(mx[reg]));
      mx[reg] = fmaxf(mx[reg], dpp_ror<0x128>(mx[reg]));
    }

    // p = exp(0.125*(s-m)) = exp2(0.18033688*(s-m)); masked entries -> 0
    constexpr float CEXP = 0.18033688011112042f;
    float sum[4] = {0.f, 0.f, 0.f, 0.f};
#pragma unroll
    for (int nt = 0; nt < 13; ++nt)
#pragma unroll
      for (int reg = 0; reg < 4; ++reg) {
        float p = exp2f((S[nt][reg] - mx[reg]) * CEXP);
        S[nt][reg] = p;
        sum[reg] += p;
      }
#pragma unroll
    for (int reg = 0; reg < 4; ++reg) {
      sum[reg] += dpp_ror<0x121>(sum[reg]);
      sum[reg] += dpp_ror<0x122>(sum[reg]);
      sum[reg] += dpp_ror<0x124>(sum[reg]);
      sum[reg] += dpp_ror<0x128>(sum[reg]);
    }
    float inv[4];
#pragma unroll
    for (int reg = 0; reg < 4; ++reg) inv[reg] = __builtin_amdgcn_rcpf(sum[reg]);

    // PV: chunked P->LDS (wave-private; DS in-order per wave makes the
    // single buffer safe).  kt<6: the key permutation puts a lane's
    // (mfrag, mfrag+16) pair at adjacent shorts -> one ds_write_b32.
    // kt=6: identity layout, split halves (upper half zero).
    f4_t o[4];
#pragma unroll
    for (int dt = 0; dt < 4; ++dt) o[dt] = (f4_t){0.f, 0.f, 0.f, 0.f};
    unsigned short* buf = Ps[wave];
#pragma unroll
    for (int kt = 0; kt < 7; ++kt) {
      if (kt < 6) {
#pragma unroll
        for (int reg = 0; reg < 4; ++reg) {
          unsigned int u = cvt_pk_bf16(S[kt * 2][reg], S[kt * 2 + 1][reg]);
          *(unsigned int*)(buf + (quad * 4 + reg) * 40 + 2 * mfrag) = u;
        }
      } else {
#pragma unroll
        for (int reg = 0; reg < 4; ++reg) {
          unsigned int u = cvt_pk_bf16(S[12][reg], 0.f);
          buf[(quad * 4 + reg) * 40 + mfrag]      = (unsigned short)u;
          buf[(quad * 4 + reg) * 40 + 16 + mfrag] = 0;
        }
      }
      bf8_t pf = *(const bf8_t*)(buf + mfrag * 40 + quad * 8);
#pragma unroll
      for (int dt = 0; dt < 4; ++dt) {
        bf8_t vf = *(const bf8_t*)(Vt + (dt * 16 + mfrag) * 232 + kt * 32 + quad * 8);
        o[dt] = __builtin_amdgcn_mfma_f32_16x16x32_bf16(pf, vf, o[dt], 0, 0, 0);
      }
    }

    // msg store: lane holds o[dt][reg] = out[q=quad*4+reg][d=dt*16+mfrag]
#pragma unroll
    for (int dt = 0; dt < 4; dt += 2)
#pragma unroll
      for (int reg = 0; reg < 4; ++reg) {
        int q = m0 + quad * 4 + reg;
        unsigned int u = cvt_pk_bf16(o[dt][reg] * inv[reg], o[dt + 1][reg] * inv[reg]);
        if (q < 197) {
          size_t base = (size_t)e * 37824 + q * 192 + h * 64 + dt * 16 + mfrag;
          msgbuf[base]      = (unsigned short)u;
          msgbuf[base + 16] = (unsigned short)(u >> 16);
        }
      }
  }
}

// ---------------------------------------------------------------------------
// Per-dst aggregation, bf16x8 vectorized.  grid (256 dst, 4 chunks).
// ---------------------------------------------------------------------------
__global__ __launch_bounds__(256) void aggregate_kernel(
    const unsigned short* __restrict__ msgbuf, const int* __restrict__ edge,
    unsigned short* __restrict__ agg, int* __restrict__ cntg) {
  const int b = blockIdx.x, chunk = blockIdx.y;
  __shared__ int list[1024];
  __shared__ int lc;
  const int tid = threadIdx.x;
  if (tid == 0) lc = 0;
  __syncthreads();
  for (int e = tid; e < 1024; e += 256)
    if (edge[1024 + e] == b) { int p = atomicAdd(&lc, 1); list[p] = e; }
  __syncthreads();
  const int cnt = lc;
  if (chunk == 0 && tid == 0) cntg[b] = cnt;
  const int base = chunk * 9456;  // 37824 = 4*9456, 9456 = 1182*8
  for (int i8 = tid; i8 < 1182; i8 += 256) {
    int i = base + i8 * 8;
    float sum[8];
#pragma unroll
    for (int kk = 0; kk < 8; ++kk) sum[kk] = 0.f;
    for (int j = 0; j < cnt; ++j) {
      float4 t = *(const float4*)(msgbuf + (size_t)list[j] * 37824 + i);
      const unsigned short* u = (const unsigned short*)&t;
#pragma unroll
      for (int kk = 0; kk < 8; ++kk) sum[kk] += bf2f(u[kk]);
    }
    unsigned short o[8];
#pragma unroll
    for (int kk = 0; kk < 8; ++kk) o[kk] = f2bf(sum[kk]);
    *(float4*)(agg + (size_t)b * 37824 + i) = *(const float4*)o;
  }
}

// ---------------------------------------------------------------------------
extern "C" void kernel_launch(void* const* d_in, const int* in_sizes, int n_in,
                              void* d_out, int out_size, void* d_ws, size_t ws_size,
                              hipStream_t stream) {
  const float* x      = (const float*)d_in[0];
  const int*   edge   = (const int*)d_in[1];
  const float* n1g    = (const float*)d_in[2];
  const float* n1b    = (const float*)d_in[3];
  const float* qkv_w  = (const float*)d_in[4];
  const float* proj_w = (const float*)d_in[5];
  const float* proj_b = (const float*)d_in[6];
  const float* n2g    = (const float*)d_in[7];
  const float* n2b    = (const float*)d_in[8];
  const float* fc1_w  = (const float*)d_in[9];
  const float* fc1_b  = (const float*)d_in[10];
  const float* fc2_w  = (const float*)d_in[11];
  const float* fc2_b  = (const float*)d_in[12];
  float* out = (float*)d_out;

  char* ws = (char*)d_ws;
  unsigned short* msgbuf = (unsigned short*)ws;
  unsigned short* h1     = (unsigned short*)ws;                    // overlays msgbuf
  unsigned short* qk     = (unsigned short*)(ws + 77463552);
  unsigned short* xn     = (unsigned short*)(ws + 116195328);
  unsigned short* agg    = (unsigned short*)(ws + 135561216);
  unsigned short* vtg    = (unsigned short*)(ws + 154927104);
  unsigned short* wqkv   = (unsigned short*)(ws + 174587904);
  unsigned short* wproj  = (unsigned short*)(ws + 174809088);
  unsigned short* wfc1   = (unsigned short*)(ws + 174882816);
  unsigned short* wfc2   = (unsigned short*)(ws + 175177728);
  int*            cntg   = (int*)           (ws + 175472640);

  dim3 blk(256);
  f2bf_kernel<<<dim3(432), blk, 0, stream>>>(qkv_w, wqkv, 110592);
  f2bf_kernel<<<dim3(144), blk, 0, stream>>>(proj_w, wproj, 36864);
  f2bf_kernel<<<dim3(576), blk, 0, stream>>>(fc1_w, wfc1, 147456);
  f2bf_kernel<<<dim3(576), blk, 0, stream>>>(fc2_w, wfc2, 147456);

  ln_bf16_kernel<<<dim3(12608), blk, 0, stream>>>(x, n1g, n1b, xn);
  gemm_bf16<0, 1><<<dim3(9, 394), blk, 0, stream>>>(xn, wqkv, nullptr, nullptr, nullptr, qk, vtg, 384);
  attnA_kernel<<<dim3(1024, 3), dim3(512), 0, stream>>>(qk, vtg, edge, msgbuf);
  aggregate_kernel<<<dim3(256, 4), blk, 0, stream>>>(msgbuf, edge, agg, cntg);
  gemm_bf16<1, 1><<<dim3(3, 394), blk, 0, stream>>>(agg, wproj, proj_b, x, cntg, out, nullptr, 192);
  ln_bf16_kernel<<<dim3(12608), blk, 0, stream>>>(out, n2g, n2b, xn);
  gemm_bf16<2, 1><<<dim3(12, 394), blk, 0, stream>>>(xn, wfc1, fc1_b, nullptr, nullptr, h1, nullptr, 768);
  gemm_bf16<3, 4><<<dim3(3, 394), blk, 0, stream>>>(h1, wfc2, fc2_b, out, nullptr, out, nullptr, 192);
}

// Round 4
// 484.068 us; speedup vs baseline: 1.1249x; 1.0553x over previous
//
#include <hip/hip_runtime.h>
#include <hip/hip_bf16.h>
#include <cstddef>

// Bn=256, N=197, C=192, H=3, hd=64, E=1024, hid=768, M = Bn*N = 50432 = 394*128
//
// ws layout (bytes):
//   [0,          77463552)   : msgbuf bf16 [1024][197][192]  -- later overlaid by h1 bf16 [50432][768]
//   [77463552,  116195328)   : qk  bf16 [50432][384]   (Q cols 0..191, K cols 192..383)
//   [116195328, 135561216)   : xn  bf16 [50432][192]   (reused as x2n after proj)
//   [135561216, 154927104)   : agg bf16 [50432][192]
//   [154927104, 174587904)   : vt  bf16 [256][3][64][200]  (V transposed, t contiguous; cols 197..199 garbage)
//   [174587904, 175472640)   : bf16 weights, contiguous: wqkv|wproj|wfc1|wfc2
//   [175472640, 175473664)   : cnt int32[256]

typedef __attribute__((ext_vector_type(8))) short bf8_t;
typedef __attribute__((ext_vector_type(4))) float f4_t;

#define GLOBAL_AS __attribute__((address_space(1)))
#define LDS_AS    __attribute__((address_space(3)))

__device__ __forceinline__ float bf2f(unsigned short u) {
  union { unsigned int i; float f; } x; x.i = ((unsigned int)u) << 16; return x.f;
}
__device__ __forceinline__ unsigned short f2bf(float f) {
  unsigned int u = __builtin_bit_cast(unsigned int, f);
  u = (u + 0x7FFFu + ((u >> 16) & 1u)) >> 16;
  return (unsigned short)u;
}
// packed f32x2 -> bf16x2 (RTNE), single VALU op (no builtin on gfx950)
__device__ __forceinline__ unsigned int cvt_pk_bf16(float a, float b) {
  unsigned int r;
  asm("v_cvt_pk_bf16_f32 %0, %1, %2" : "=v"(r) : "v"(a), "v"(b));
  return r;
}
// async global->LDS, 16B per lane; LDS dest = base + lane*16 (linear), global src per-lane
__device__ __forceinline__ void gload16(const unsigned short* g, unsigned short* l) {
  __builtin_amdgcn_global_load_lds((const GLOBAL_AS unsigned int*)g,
                                   (LDS_AS unsigned int*)l, 16, 0, 0);
}

// ---------------------------------------------------------------------------
// All four weight matrices -> bf16, one launch (dst regions are contiguous).
// sizes: qkv 110592 | proj 36864 | fc1 147456 | fc2 147456  (total 442368)
// ---------------------------------------------------------------------------
__global__ __launch_bounds__(256) void wcvt_kernel(
    const float* __restrict__ qkvw, const float* __restrict__ projw,
    const float* __restrict__ fc1w, const float* __restrict__ fc2w,
    unsigned short* __restrict__ dst) {
  int i = blockIdx.x * 256 + threadIdx.x;
  float v;
  if (i < 110592)      v = qkvw[i];
  else if (i < 147456) v = projw[i - 110592];
  else if (i < 294912) v = fc1w[i - 147456];
  else                 v = fc2w[i - 294912];
  dst[i] = f2bf(v);
}

// ---------------------------------------------------------------------------
// LayerNorm(fp32 in) -> bf16 out.  One wave per row (C=192, 3 elems/lane).
// ---------------------------------------------------------------------------
__global__ __launch_bounds__(256) void ln_bf16_kernel(const float* __restrict__ X,
    const float* __restrict__ g, const float* __restrict__ b,
    unsigned short* __restrict__ Y) {
  int row = blockIdx.x * 4 + (threadIdx.x >> 6);
  int lane = threadIdx.x & 63;
  const float* xr = X + (size_t)row * 192;
  float v0 = xr[lane], v1 = xr[lane + 64], v2 = xr[lane + 128];
  float s = v0 + v1 + v2, ss = v0 * v0 + v1 * v1 + v2 * v2;
#pragma unroll
  for (int o = 32; o > 0; o >>= 1) { s += __shfl_xor(s, o, 64); ss += __shfl_xor(ss, o, 64); }
  float mean = s * (1.f / 192.f);
  float var = ss * (1.f / 192.f) - mean * mean;
  float r = rsqrtf(var + 1e-5f);
  unsigned short* yr = Y + (size_t)row * 192;
  yr[lane]       = f2bf((v0 - mean) * r * g[lane]       + b[lane]);
  yr[lane + 64]  = f2bf((v1 - mean) * r * g[lane + 64]  + b[lane + 64]);
  yr[lane + 128] = f2bf((v2 - mean) * r * g[lane + 128] + b[lane + 128]);
}

// ---------------------------------------------------------------------------
// bf16 MFMA GEMM: C = f( A @ W^T ), tile 128x64, 4 waves.
// Staging via global_load_lds width=16 (no VGPR roundtrip, no addr-calc VALU).
// LDS rows padded to LDA=208 shorts (stride 416B = 104 dw == 8 mod 32 -> 4-way
// ds_read conflicts, near-free); pad lanes DMA clamped duplicate data.
// MODE 0: qkv -> qk bf16 (cols<384) + vt bf16 transposed (cols>=384)
// MODE 1: proj -> f32 (/cnt, +bias, +xres)
// MODE 2: fc1 -> bf16 gelu(+bias)
// MODE 3: fc2 -> f32 (+bias, +xres; in-place safe per-element)
// ---------------------------------------------------------------------------
template<int MODE, int NK>
__global__ __launch_bounds__(256) void gemm_bf16(
    const unsigned short* __restrict__ A, const unsigned short* __restrict__ W,
    const float* __restrict__ bias, const float* __restrict__ xres,
    const int* __restrict__ cntg, void* __restrict__ Cout,
    unsigned short* __restrict__ Cvt, int ldc) {
  constexpr int LDA = 208;                 // shorts; 26 16B-segments per row
  __shared__ unsigned short As[128 * LDA]; // 52 chunks of 1024B
  __shared__ unsigned short Ws[64 * LDA];  // 26 chunks of 1024B
  const int tid = threadIdx.x;
  const int m0 = blockIdx.x * 128, n0 = blockIdx.y * 64;
  const int wave = tid >> 6, lane = tid & 63;
  const int mfrag = lane & 15, quad = lane >> 4;
  const int K = NK * 192;

  f4_t acc[2][4];
#pragma unroll
  for (int i = 0; i < 2; ++i)
#pragma unroll
    for (int j = 0; j < 4; ++j) acc[i][j] = (f4_t){0.f, 0.f, 0.f, 0.f};

  for (int kc = 0; kc < NK; ++kc) {
    __syncthreads();
    // 78 DMA chunks total (52 A + 26 W), round-robined across the 4 waves.
    for (int it = wave; it < 78; it += 4) {
      if (it < 52) {
        int idx = it * 64 + lane;          // 0..3327
        int r = idx / 26, c = idx % 26;
        int c8 = min(c * 8, 184);          // clamp pad lanes inside the row
        gload16(A + (size_t)(m0 + r) * K + kc * 192 + c8, As + it * 512);
      } else {
        int idx = (it - 52) * 64 + lane;   // 0..1663
        int r = idx / 26, c = idx % 26;
        int c8 = min(c * 8, 184);
        gload16(W + (size_t)(n0 + r) * K + kc * 192 + c8, Ws + (it - 52) * 512);
      }
    }
    __syncthreads();
#pragma unroll
    for (int ks = 0; ks < 6; ++ks) {
      bf8_t a0 = *(const bf8_t*)(As + (wave * 32 + mfrag) * LDA + ks * 32 + quad * 8);
      bf8_t a1 = *(const bf8_t*)(As + (wave * 32 + 16 + mfrag) * LDA + ks * 32 + quad * 8);
#pragma unroll
      for (int nt = 0; nt < 4; ++nt) {
        bf8_t bf = *(const bf8_t*)(Ws + (nt * 16 + mfrag) * LDA + ks * 32 + quad * 8);
        acc[0][nt] = __builtin_amdgcn_mfma_f32_16x16x32_bf16(a0, bf, acc[0][nt], 0, 0, 0);
        acc[1][nt] = __builtin_amdgcn_mfma_f32_16x16x32_bf16(a1, bf, acc[1][nt], 0, 0, 0);
      }
    }
  }

#pragma unroll
  for (int mt = 0; mt < 2; ++mt)
#pragma unroll
    for (int nt = 0; nt < 4; ++nt)
#pragma unroll
      for (int reg = 0; reg < 4; ++reg) {
        int row = m0 + wave * 32 + mt * 16 + quad * 4 + reg;
        int col = n0 + nt * 16 + mfrag;
        float v = acc[mt][nt][reg];
        if constexpr (MODE == 0) {
          if (col < 384) {
            ((unsigned short*)Cout)[(size_t)row * 384 + col] = f2bf(v);
          } else {
            int cc = col - 384, hh = cc >> 6, dd = cc & 63;
            int bb = row / 197, tt = row - bb * 197;
            Cvt[((size_t)(bb * 3 + hh) * 64 + dd) * 200 + tt] = f2bf(v);
          }
        } else if constexpr (MODE == 1) {
          int c = cntg[row / 197];
          v = (c > 0) ? v / (float)c + bias[col] : 0.f;
          v += xres[(size_t)row * 192 + col];
          ((float*)Cout)[(size_t)row * ldc + col] = v;
        } else if constexpr (MODE == 2) {
          v += bias[col];
          v = 0.5f * v * (1.f + erff(v * 0.70710678118654752f));
          ((unsigned short*)Cout)[(size_t)row * ldc + col] = f2bf(v);
        } else {
          v += bias[col] + xres[(size_t)row * 192 + col];
          ((float*)Cout)[(size_t)row * ldc + col] = v;
        }
      }
}

// ---------------------------------------------------------------------------
// MFMA attention (R1-exact, 110 us / VGPR 56 known-good).  One block per
// (edge e, head h); 512 threads / 8 waves.  K staged row-major from qk;
// V^T staged from pre-transposed vt.  S = Q@K^T, exact softmax in regs
// (exp2-folded scale, tail-only masking), P->LDS (single wave-private
// buffer, in-order DS) -> PV -> msgbuf.
// ---------------------------------------------------------------------------
__global__ __launch_bounds__(512) void attnA_kernel(
    const unsigned short* __restrict__ qk, const unsigned short* __restrict__ vtg,
    const int* __restrict__ edge, unsigned short* __restrict__ msgbuf) {
  const int e = blockIdx.x, h = blockIdx.y;
  const int s = edge[e], b = edge[1024 + e];
  __shared__ unsigned short Ks[208 * 72];
  __shared__ unsigned short Vt[64 * 232];
  __shared__ unsigned short Ps[8][640];   // [wave][16*40], single buffer (DS in-order per wave)
  const int tid = threadIdx.x;
  const int wave = tid >> 6, lane = tid & 63;
  const int mfrag = lane & 15, quad = lane >> 4;

  // stage K rows (src s), coalesced 16B, conflict-free
  for (int i = tid; i < 197 * 8; i += 512) {
    int m = i >> 3, c8 = i & 7;
    *(float4*)(Ks + m * 72 + c8 * 8) =
        *(const float4*)(qk + (size_t)(s * 197 + m) * 384 + 192 + h * 64 + c8 * 8);
  }
  // stage V^T rows (dst b) from pre-transposed global, b128 conflict-free
  for (int i = tid; i < 64 * 25; i += 512) {
    int d = i / 25, c8 = i - d * 25;
    *(float4*)(Vt + d * 232 + c8 * 8) =
        *(const float4*)(vtg + ((size_t)(b * 3 + h) * 64 + d) * 200 + c8 * 8);
  }
  __syncthreads();
  // zero pad keys 197..231 (197..199 overwrite staged garbage)
  for (int i = tid; i < 64 * 35; i += 512) {
    int d = i / 35, kk = 197 + (i - d * 35);
    Vt[d * 232 + kk] = 0;
  }
  __syncthreads();

  for (int st = wave; st < 13; st += 8) {
    const int m0 = st * 16;
    const size_t qrow = (size_t)(b * 197 + min(m0 + mfrag, 196)) * 384 + h * 64;
    bf8_t a0 = *(const bf8_t*)(qk + qrow + quad * 8);
    bf8_t a1 = *(const bf8_t*)(qk + qrow + 32 + quad * 8);

    f4_t S[13];
#pragma unroll
    for (int nt = 0; nt < 13; ++nt) {
      bf8_t k0 = *(const bf8_t*)(Ks + (nt * 16 + mfrag) * 72 + quad * 8);
      bf8_t k1 = *(const bf8_t*)(Ks + (nt * 16 + mfrag) * 72 + 32 + quad * 8);
      f4_t z = (f4_t){0.f, 0.f, 0.f, 0.f};
      z = __builtin_amdgcn_mfma_f32_16x16x32_bf16(a0, k0, z, 0, 0, 0);
      S[nt] = __builtin_amdgcn_mfma_f32_16x16x32_bf16(a1, k1, z, 0, 0, 0);
    }

    // exact softmax over keys; lane holds S[q=quad*4+reg][key=nt*16+mfrag].
    // only nt=12 has invalid keys (192..207): mask those lanes once.
#pragma unroll
    for (int reg = 0; reg < 4; ++reg)
      S[12][reg] = (mfrag < 5) ? S[12][reg] : -1e30f;

    float mx[4] = {-1e30f, -1e30f, -1e30f, -1e30f};
#pragma unroll
    for (int nt = 0; nt < 13; ++nt)
#pragma unroll
      for (int reg = 0; reg < 4; ++reg) mx[reg] = fmaxf(mx[reg], S[nt][reg]);
#pragma unroll
    for (int off = 1; off < 16; off <<= 1)
#pragma unroll
      for (int reg = 0; reg < 4; ++reg) mx[reg] = fmaxf(mx[reg], __shfl_xor(mx[reg], off, 64));

    // p = exp(0.125*(s-m)) = exp2(0.18033688*(s-m)); masked entries -> 0
    constexpr float CEXP = 0.18033688011112042f;
    float sum[4] = {0.f, 0.f, 0.f, 0.f};
#pragma unroll
    for (int nt = 0; nt < 13; ++nt)
#pragma unroll
      for (int reg = 0; reg < 4; ++reg) {
        float p = exp2f((S[nt][reg] - mx[reg]) * CEXP);
        S[nt][reg] = p;
        sum[reg] += p;
      }
#pragma unroll
    for (int off = 1; off < 16; off <<= 1)
#pragma unroll
      for (int reg = 0; reg < 4; ++reg) sum[reg] += __shfl_xor(sum[reg], off, 64);
    float inv[4];
#pragma unroll
    for (int reg = 0; reg < 4; ++reg) inv[reg] = __builtin_amdgcn_rcpf(sum[reg]);

    // PV: chunked P->LDS (wave-private; DS in-order per wave makes the
    // single buffer safe: the pf read of chunk kt is issued before chunk
    // kt+1's writes and the DS pipe processes same-wave ops in order).
    f4_t o[4];
#pragma unroll
    for (int dt = 0; dt < 4; ++dt) o[dt] = (f4_t){0.f, 0.f, 0.f, 0.f};
    unsigned short* buf = Ps[wave];
#pragma unroll
    for (int kt = 0; kt < 7; ++kt) {
#pragma unroll
      for (int reg = 0; reg < 4; ++reg) {
        float p0 = S[kt * 2][reg];
        float p1 = (kt * 2 + 1 < 13) ? S[kt * 2 + 1][reg] : 0.f;
        unsigned int u = cvt_pk_bf16(p0, p1);
        buf[(quad * 4 + reg) * 40 + mfrag]      = (unsigned short)u;
        buf[(quad * 4 + reg) * 40 + 16 + mfrag] = (unsigned short)(u >> 16);
      }
      bf8_t pf = *(const bf8_t*)(buf + mfrag * 40 + quad * 8);
#pragma unroll
      for (int dt = 0; dt < 4; ++dt) {
        bf8_t vf = *(const bf8_t*)(Vt + (dt * 16 + mfrag) * 232 + kt * 32 + quad * 8);
        o[dt] = __builtin_amdgcn_mfma_f32_16x16x32_bf16(pf, vf, o[dt], 0, 0, 0);
      }
    }

    // msg store: lane holds o[dt][reg] = out[q=quad*4+reg][d=dt*16+mfrag]
#pragma unroll
    for (int dt = 0; dt < 4; dt += 2)
#pragma unroll
      for (int reg = 0; reg < 4; ++reg) {
        int q = m0 + quad * 4 + reg;
        unsigned int u = cvt_pk_bf16(o[dt][reg] * inv[reg], o[dt + 1][reg] * inv[reg]);
        if (q < 197) {
          size_t base = (size_t)e * 37824 + q * 192 + h * 64 + dt * 16 + mfrag;
          msgbuf[base]      = (unsigned short)u;
          msgbuf[base + 16] = (unsigned short)(u >> 16);
        }
      }
  }
}

// ---------------------------------------------------------------------------
// Per-dst aggregation, bf16x8 vectorized.  grid (256 dst, 4 chunks).
// ---------------------------------------------------------------------------
__global__ __launch_bounds__(256) void aggregate_kernel(
    const unsigned short* __restrict__ msgbuf, const int* __restrict__ edge,
    unsigned short* __restrict__ agg, int* __restrict__ cntg) {
  const int b = blockIdx.x, chunk = blockIdx.y;
  __shared__ int list[1024];
  __shared__ int lc;
  const int tid = threadIdx.x;
  if (tid == 0) lc = 0;
  __syncthreads();
  for (int e = tid; e < 1024; e += 256)
    if (edge[1024 + e] == b) { int p = atomicAdd(&lc, 1); list[p] = e; }
  __syncthreads();
  const int cnt = lc;
  if (chunk == 0 && tid == 0) cntg[b] = cnt;
  const int base = chunk * 9456;  // 37824 = 4*9456, 9456 = 1182*8
  for (int i8 = tid; i8 < 1182; i8 += 256) {
    int i = base + i8 * 8;
    float sum[8];
#pragma unroll
    for (int kk = 0; kk < 8; ++kk) sum[kk] = 0.f;
    for (int j = 0; j < cnt; ++j) {
      float4 t = *(const float4*)(msgbuf + (size_t)list[j] * 37824 + i);
      const unsigned short* u = (const unsigned short*)&t;
#pragma unroll
      for (int kk = 0; kk < 8; ++kk) sum[kk] += bf2f(u[kk]);
    }
    unsigned short o[8];
#pragma unroll
    for (int kk = 0; kk < 8; ++kk) o[kk] = f2bf(sum[kk]);
    *(float4*)(agg + (size_t)b * 37824 + i) = *(const float4*)o;
  }
}

// ---------------------------------------------------------------------------
extern "C" void kernel_launch(void* const* d_in, const int* in_sizes, int n_in,
                              void* d_out, int out_size, void* d_ws, size_t ws_size,
                              hipStream_t stream) {
  const float* x      = (const float*)d_in[0];
  const int*   edge   = (const int*)d_in[1];
  const float* n1g    = (const float*)d_in[2];
  const float* n1b    = (const float*)d_in[3];
  const float* qkv_w  = (const float*)d_in[4];
  const float* proj_w = (const float*)d_in[5];
  const float* proj_b = (const float*)d_in[6];
  const float* n2g    = (const float*)d_in[7];
  const float* n2b    = (const float*)d_in[8];
  const float* fc1_w  = (const float*)d_in[9];
  const float* fc1_b  = (const float*)d_in[10];
  const float* fc2_w  = (const float*)d_in[11];
  const float* fc2_b  = (const float*)d_in[12];
  float* out = (float*)d_out;

  char* ws = (char*)d_ws;
  unsigned short* msgbuf = (unsigned short*)ws;
  unsigned short* h1     = (unsigned short*)ws;                    // overlays msgbuf
  unsigned short* qk     = (unsigned short*)(ws + 77463552);
  unsigned short* xn     = (unsigned short*)(ws + 116195328);
  unsigned short* agg    = (unsigned short*)(ws + 135561216);
  unsigned short* vtg    = (unsigned short*)(ws + 154927104);
  unsigned short* wqkv   = (unsigned short*)(ws + 174587904);
  unsigned short* wproj  = (unsigned short*)(ws + 174809088);
  unsigned short* wfc1   = (unsigned short*)(ws + 174882816);
  unsigned short* wfc2   = (unsigned short*)(ws + 175177728);
  int*            cntg   = (int*)           (ws + 175472640);

  dim3 blk(256);
  wcvt_kernel<<<dim3(1728), blk, 0, stream>>>(qkv_w, proj_w, fc1_w, fc2_w, wqkv);

  ln_bf16_kernel<<<dim3(12608), blk, 0, stream>>>(x, n1g, n1b, xn);
  gemm_bf16<0, 1><<<dim3(394, 9), blk, 0, stream>>>(xn, wqkv, nullptr, nullptr, nullptr, qk, vtg, 384);
  attnA_kernel<<<dim3(1024, 3), dim3(512), 0, stream>>>(qk, vtg, edge, msgbuf);
  aggregate_kernel<<<dim3(256, 4), blk, 0, stream>>>(msgbuf, edge, agg, cntg);
  gemm_bf16<1, 1><<<dim3(394, 3), blk, 0, stream>>>(agg, wproj, proj_b, x, cntg, out, nullptr, 192);
  ln_bf16_kernel<<<dim3(12608), blk, 0, stream>>>(out, n2g, n2b, xn);
  gemm_bf16<2, 1><<<dim3(394, 12), blk, 0, stream>>>(xn, wfc1, fc1_b, nullptr, nullptr, h1, nullptr, 768);
  gemm_bf16<3, 4><<<dim3(394, 3), blk, 0, stream>>>(h1, wfc2, fc2_b, out, nullptr, out, nullptr, 192);
}

// Round 7
// 449.174 us; speedup vs baseline: 1.2122x; 1.0777x over previous
//
#include <hip/hip_runtime.h>
#include <hip/hip_bf16.h>
#include <cstddef>

// Bn=256, N=197, C=192, H=3, hd=64, E=1024, hid=768, M = Bn*N = 50432 = 394*128
//
// ws layout (bytes):
//   [0,          77463552)   : msgbuf bf16 [1024][197][192]  -- later overlaid by h1 bf16 [50432][768]
//   [77463552,  116195328)   : qk  bf16 [50432][384]   (Q cols 0..191, K cols 192..383)
//   [116195328, 135561216)   : xn  bf16 [50432][192]   (reused as x2n after proj+LN2 fusion)
//   [135561216, 154927104)   : agg bf16 [50432][192]
//   [154927104, 174587904)   : vt  bf16 [256][3][64][200]  (V transposed, t contiguous; cols 197..199 garbage)
//   [174587904, 175472640)   : bf16 weights, contiguous: wqkv|wproj|wfc1|wfc2
//   [175472640, 175473664)   : cnt int32[256]

typedef __attribute__((ext_vector_type(8))) short bf8_t;
typedef __attribute__((ext_vector_type(4))) float f4_t;

#define GLOBAL_AS __attribute__((address_space(1)))
#define LDS_AS    __attribute__((address_space(3)))

__device__ __forceinline__ float bf2f(unsigned short u) {
  union { unsigned int i; float f; } x; x.i = ((unsigned int)u) << 16; return x.f;
}
__device__ __forceinline__ unsigned short f2bf(float f) {
  unsigned int u = __builtin_bit_cast(unsigned int, f);
  u = (u + 0x7FFFu + ((u >> 16) & 1u)) >> 16;
  return (unsigned short)u;
}
// packed f32x2 -> bf16x2 (RTNE), single VALU op (no builtin on gfx950)
__device__ __forceinline__ unsigned int cvt_pk_bf16(float a, float b) {
  unsigned int r;
  asm("v_cvt_pk_bf16_f32 %0, %1, %2" : "=v"(r) : "v"(a), "v"(b));
  return r;
}
// async global->LDS, 16B per lane; LDS dest = base + lane*16 (linear), global src per-lane
__device__ __forceinline__ void gload16(const unsigned short* g, unsigned short* l) {
  __builtin_amdgcn_global_load_lds((const GLOBAL_AS unsigned int*)g,
                                   (LDS_AS unsigned int*)l, 16, 0, 0);
}

// ---------------------------------------------------------------------------
// All four weight matrices -> bf16, one launch (dst regions are contiguous).
// ---------------------------------------------------------------------------
__global__ __launch_bounds__(256) void wcvt_kernel(
    const float* __restrict__ qkvw, const float* __restrict__ projw,
    const float* __restrict__ fc1w, const float* __restrict__ fc2w,
    unsigned short* __restrict__ dst) {
  int i = blockIdx.x * 256 + threadIdx.x;
  float v;
  if (i < 110592)      v = qkvw[i];
  else if (i < 147456) v = projw[i - 110592];
  else if (i < 294912) v = fc1w[i - 147456];
  else                 v = fc2w[i - 294912];
  dst[i] = f2bf(v);
}

// ---------------------------------------------------------------------------
// LayerNorm(fp32 in) -> bf16 out.  One wave per row (C=192, 3 elems/lane).
// ---------------------------------------------------------------------------
__global__ __launch_bounds__(256) void ln_bf16_kernel(const float* __restrict__ X,
    const float* __restrict__ g, const float* __restrict__ b,
    unsigned short* __restrict__ Y) {
  int row = blockIdx.x * 4 + (threadIdx.x >> 6);
  int lane = threadIdx.x & 63;
  const float* xr = X + (size_t)row * 192;
  float v0 = xr[lane], v1 = xr[lane + 64], v2 = xr[lane + 128];
  float s = v0 + v1 + v2, ss = v0 * v0 + v1 * v1 + v2 * v2;
#pragma unroll
  for (int o = 32; o > 0; o >>= 1) { s += __shfl_xor(s, o, 64); ss += __shfl_xor(ss, o, 64); }
  float mean = s * (1.f / 192.f);
  float var = ss * (1.f / 192.f) - mean * mean;
  float r = rsqrtf(var + 1e-5f);
  unsigned short* yr = Y + (size_t)row * 192;
  yr[lane]       = f2bf((v0 - mean) * r * g[lane]       + b[lane]);
  yr[lane + 64]  = f2bf((v1 - mean) * r * g[lane + 64]  + b[lane + 64]);
  yr[lane + 128] = f2bf((v2 - mean) * r * g[lane + 128] + b[lane + 128]);
}

// ---------------------------------------------------------------------------
// bf16 MFMA GEMM: C = f( A @ W^T ), tile 128x64, 4 waves.
// Staging via global_load_lds width=16.  LDA=208 shorts.
// MODE 0: qkv -> qk bf16 (cols<384) + vt bf16 transposed (cols>=384)
// MODE 2: fc1 -> bf16 gelu(+bias)
// MODE 3: fc2 -> f32 (+bias, +xres; in-place safe per-element)
// ---------------------------------------------------------------------------
template<int MODE, int NK>
__global__ __launch_bounds__(256) void gemm_bf16(
    const unsigned short* __restrict__ A, const unsigned short* __restrict__ W,
    const float* __restrict__ bias, const float* __restrict__ xres,
    const int* __restrict__ cntg, void* __restrict__ Cout,
    unsigned short* __restrict__ Cvt, int ldc) {
  constexpr int LDA = 208;                 // shorts; 26 16B-segments per row
  __shared__ unsigned short As[128 * LDA]; // 52 chunks of 1024B
  __shared__ unsigned short Ws[64 * LDA];  // 26 chunks of 1024B
  const int tid = threadIdx.x;
  const int m0 = blockIdx.x * 128, n0 = blockIdx.y * 64;
  const int wave = tid >> 6, lane = tid & 63;
  const int mfrag = lane & 15, quad = lane >> 4;
  const int K = NK * 192;

  f4_t acc[2][4];
#pragma unroll
  for (int i = 0; i < 2; ++i)
#pragma unroll
    for (int j = 0; j < 4; ++j) acc[i][j] = (f4_t){0.f, 0.f, 0.f, 0.f};

  for (int kc = 0; kc < NK; ++kc) {
    __syncthreads();
    for (int it = wave; it < 78; it += 4) {
      if (it < 52) {
        int idx = it * 64 + lane;
        int r = idx / 26, c = idx % 26;
        int c8 = min(c * 8, 184);
        gload16(A + (size_t)(m0 + r) * K + kc * 192 + c8, As + it * 512);
      } else {
        int idx = (it - 52) * 64 + lane;
        int r = idx / 26, c = idx % 26;
        int c8 = min(c * 8, 184);
        gload16(W + (size_t)(n0 + r) * K + kc * 192 + c8, Ws + (it - 52) * 512);
      }
    }
    __syncthreads();
#pragma unroll
    for (int ks = 0; ks < 6; ++ks) {
      bf8_t a0 = *(const bf8_t*)(As + (wave * 32 + mfrag) * LDA + ks * 32 + quad * 8);
      bf8_t a1 = *(const bf8_t*)(As + (wave * 32 + 16 + mfrag) * LDA + ks * 32 + quad * 8);
#pragma unroll
      for (int nt = 0; nt < 4; ++nt) {
        bf8_t bf = *(const bf8_t*)(Ws + (nt * 16 + mfrag) * LDA + ks * 32 + quad * 8);
        acc[0][nt] = __builtin_amdgcn_mfma_f32_16x16x32_bf16(a0, bf, acc[0][nt], 0, 0, 0);
        acc[1][nt] = __builtin_amdgcn_mfma_f32_16x16x32_bf16(a1, bf, acc[1][nt], 0, 0, 0);
      }
    }
  }

#pragma unroll
  for (int mt = 0; mt < 2; ++mt)
#pragma unroll
    for (int nt = 0; nt < 4; ++nt)
#pragma unroll
      for (int reg = 0; reg < 4; ++reg) {
        int row = m0 + wave * 32 + mt * 16 + quad * 4 + reg;
        int col = n0 + nt * 16 + mfrag;
        float v = acc[mt][nt][reg];
        if constexpr (MODE == 0) {
          if (col < 384) {
            ((unsigned short*)Cout)[(size_t)row * 384 + col] = f2bf(v);
          } else {
            int cc = col - 384, hh = cc >> 6, dd = cc & 63;
            int bb = row / 197, tt = row - bb * 197;
            Cvt[((size_t)(bb * 3 + hh) * 64 + dd) * 200 + tt] = f2bf(v);
          }
        } else if constexpr (MODE == 2) {
          v += bias[col];
          v = 0.5f * v * (1.f + erff(v * 0.70710678118654752f));
          ((unsigned short*)Cout)[(size_t)row * ldc + col] = f2bf(v);
        } else {
          v += bias[col] + xres[(size_t)row * 192 + col];
          ((float*)Cout)[(size_t)row * ldc + col] = v;
        }
      }
}

// ---------------------------------------------------------------------------
// proj GEMM (128x192 per block, N looped in 3 chunks of 64) fused with the
// /cnt + bias + residual epilogue AND LayerNorm2.  Grid (394).  Each lane's
// (quad,reg) pair fixes a row; its 192 cols live in the 16-lane mfrag group
// (12 frags/lane), so LN stats need only 4 shfl_xor.  Emits out f32 (for
// MODE3 xres) and xn bf16 (fc1 input) -- eliminates the ln2 kernel and a
// 38 MB out re-read.
// ---------------------------------------------------------------------------
__global__ __launch_bounds__(256) void proj_ln_kernel(
    const unsigned short* __restrict__ A,   // agg bf16 [M][192]
    const unsigned short* __restrict__ W,   // wproj bf16 [192][192]
    const float* __restrict__ bias,         // proj_b
    const float* __restrict__ xres,         // x (input, f32)
    const int* __restrict__ cntg,
    const float* __restrict__ g2, const float* __restrict__ b2,
    float* __restrict__ outF,               // out f32 [M][192]
    unsigned short* __restrict__ xnout) {   // xn bf16 [M][192]
  constexpr int LDA = 208;
  __shared__ unsigned short As[128 * LDA];
  __shared__ unsigned short Ws[64 * LDA];
  const int tid = threadIdx.x;
  const int m0 = blockIdx.x * 128;
  const int wave = tid >> 6, lane = tid & 63;
  const int mfrag = lane & 15, quad = lane >> 4;

  f4_t acc[3][2][4];
#pragma unroll
  for (int nc = 0; nc < 3; ++nc)
#pragma unroll
    for (int i = 0; i < 2; ++i)
#pragma unroll
      for (int j = 0; j < 4; ++j) acc[nc][i][j] = (f4_t){0.f, 0.f, 0.f, 0.f};

  // stage A once (52 chunks; it*512 + lane*8 == r*208 + c*8 since 208 = 26*8)
  for (int it = wave; it < 52; it += 4) {
    int idx = it * 64 + lane;
    int r = idx / 26, c = idx % 26;
    int c8 = min(c * 8, 184);
    gload16(A + (size_t)(m0 + r) * 192 + c8, As + it * 512);
  }

  for (int nc = 0; nc < 3; ++nc) {
    if (nc > 0) __syncthreads();   // prior chunk's Ws readers done
    for (int it = wave; it < 26; it += 4) {
      int idx = it * 64 + lane;
      int r = idx / 26, c = idx % 26;
      int c8 = min(c * 8, 184);
      gload16(W + (size_t)(nc * 64 + r) * 192 + c8, Ws + it * 512);
    }
    __syncthreads();               // staging drained (A too, on nc=0)
#pragma unroll
    for (int ks = 0; ks < 6; ++ks) {
      bf8_t a0 = *(const bf8_t*)(As + (wave * 32 + mfrag) * LDA + ks * 32 + quad * 8);
      bf8_t a1 = *(const bf8_t*)(As + (wave * 32 + 16 + mfrag) * LDA + ks * 32 + quad * 8);
#pragma unroll
      for (int nt = 0; nt < 4; ++nt) {
        bf8_t bf = *(const bf8_t*)(Ws + (nt * 16 + mfrag) * LDA + ks * 32 + quad * 8);
        acc[nc][0][nt] = __builtin_amdgcn_mfma_f32_16x16x32_bf16(a0, bf, acc[nc][0][nt], 0, 0, 0);
        acc[nc][1][nt] = __builtin_amdgcn_mfma_f32_16x16x32_bf16(a1, bf, acc[nc][1][nt], 0, 0, 0);
      }
    }
  }

  // per-lane column params (col = nc*64 + nt*16 + mfrag, independent of row)
  float pb[12], pg[12], pbb[12];
#pragma unroll
  for (int nc = 0; nc < 3; ++nc)
#pragma unroll
    for (int nt = 0; nt < 4; ++nt) {
      int col = nc * 64 + nt * 16 + mfrag;
      pb[nc * 4 + nt] = bias[col];
      pg[nc * 4 + nt] = g2[col];
      pbb[nc * 4 + nt] = b2[col];
    }

#pragma unroll
  for (int mt = 0; mt < 2; ++mt)
#pragma unroll
    for (int reg = 0; reg < 4; ++reg) {
      const int row = m0 + wave * 32 + mt * 16 + quad * 4 + reg;
      const int cn = cntg[row / 197];
      const float rc = (cn > 0) ? 1.f / (float)cn : 0.f;
      float vv[12];
      float s = 0.f, ss = 0.f;
#pragma unroll
      for (int nc = 0; nc < 3; ++nc)
#pragma unroll
        for (int nt = 0; nt < 4; ++nt) {
          int col = nc * 64 + nt * 16 + mfrag;
          float v = (cn > 0) ? acc[nc][mt][nt][reg] * rc + pb[nc * 4 + nt] : 0.f;
          v += xres[(size_t)row * 192 + col];
          vv[nc * 4 + nt] = v;
          s += v;
          ss += v * v;
        }
      // row reduction across the 16-lane mfrag group (same row: row dep. only
      // on quad/reg; shfl_xor off<16 stays within the quad's 16 lanes)
#pragma unroll
      for (int off = 1; off < 16; off <<= 1) {
        s += __shfl_xor(s, off, 64);
        ss += __shfl_xor(ss, off, 64);
      }
      const float mean = s * (1.f / 192.f);
      const float var = ss * (1.f / 192.f) - mean * mean;
      const float r = rsqrtf(var + 1e-5f);
#pragma unroll
      for (int nc = 0; nc < 3; ++nc)
#pragma unroll
        for (int nt = 0; nt < 4; ++nt) {
          int col = nc * 64 + nt * 16 + mfrag;
          float v = vv[nc * 4 + nt];
          outF[(size_t)row * 192 + col] = v;
          xnout[(size_t)row * 192 + col] =
              f2bf((v - mean) * r * pg[nc * 4 + nt] + pbb[nc * 4 + nt]);
        }
    }
}

// ---------------------------------------------------------------------------
// MFMA attention (R1/R4-exact known-good).  One block per (edge e, head h);
// 512 threads / 8 waves.
// ---------------------------------------------------------------------------
__global__ __launch_bounds__(512) void attnA_kernel(
    const unsigned short* __restrict__ qk, const unsigned short* __restrict__ vtg,
    const int* __restrict__ edge, unsigned short* __restrict__ msgbuf) {
  const int e = blockIdx.x, h = blockIdx.y;
  const int s = edge[e], b = edge[1024 + e];
  __shared__ unsigned short Ks[208 * 72];
  __shared__ unsigned short Vt[64 * 232];
  __shared__ unsigned short Ps[8][640];   // [wave][16*40], single buffer (DS in-order per wave)
  const int tid = threadIdx.x;
  const int wave = tid >> 6, lane = tid & 63;
  const int mfrag = lane & 15, quad = lane >> 4;

  // stage K rows (src s), coalesced 16B, conflict-free
  for (int i = tid; i < 197 * 8; i += 512) {
    int m = i >> 3, c8 = i & 7;
    *(float4*)(Ks + m * 72 + c8 * 8) =
        *(const float4*)(qk + (size_t)(s * 197 + m) * 384 + 192 + h * 64 + c8 * 8);
  }
  // stage V^T rows (dst b) from pre-transposed global, b128 conflict-free
  for (int i = tid; i < 64 * 25; i += 512) {
    int d = i / 25, c8 = i - d * 25;
    *(float4*)(Vt + d * 232 + c8 * 8) =
        *(const float4*)(vtg + ((size_t)(b * 3 + h) * 64 + d) * 200 + c8 * 8);
  }
  __syncthreads();
  // zero pad keys 197..231 (197..199 overwrite staged garbage)
  for (int i = tid; i < 64 * 35; i += 512) {
    int d = i / 35, kk = 197 + (i - d * 35);
    Vt[d * 232 + kk] = 0;
  }
  __syncthreads();

  for (int st = wave; st < 13; st += 8) {
    const int m0 = st * 16;
    const size_t qrow = (size_t)(b * 197 + min(m0 + mfrag, 196)) * 384 + h * 64;
    bf8_t a0 = *(const bf8_t*)(qk + qrow + quad * 8);
    bf8_t a1 = *(const bf8_t*)(qk + qrow + 32 + quad * 8);

    f4_t S[13];
#pragma unroll
    for (int nt = 0; nt < 13; ++nt) {
      bf8_t k0 = *(const bf8_t*)(Ks + (nt * 16 + mfrag) * 72 + quad * 8);
      bf8_t k1 = *(const bf8_t*)(Ks + (nt * 16 + mfrag) * 72 + 32 + quad * 8);
      f4_t z = (f4_t){0.f, 0.f, 0.f, 0.f};
      z = __builtin_amdgcn_mfma_f32_16x16x32_bf16(a0, k0, z, 0, 0, 0);
      S[nt] = __builtin_amdgcn_mfma_f32_16x16x32_bf16(a1, k1, z, 0, 0, 0);
    }

    // exact softmax over keys; lane holds S[q=quad*4+reg][key=nt*16+mfrag].
#pragma unroll
    for (int reg = 0; reg < 4; ++reg)
      S[12][reg] = (mfrag < 5) ? S[12][reg] : -1e30f;

    float mx[4] = {-1e30f, -1e30f, -1e30f, -1e30f};
#pragma unroll
    for (int nt = 0; nt < 13; ++nt)
#pragma unroll
      for (int reg = 0; reg < 4; ++reg) mx[reg] = fmaxf(mx[reg], S[nt][reg]);
#pragma unroll
    for (int off = 1; off < 16; off <<= 1)
#pragma unroll
      for (int reg = 0; reg < 4; ++reg) mx[reg] = fmaxf(mx[reg], __shfl_xor(mx[reg], off, 64));

    constexpr float CEXP = 0.18033688011112042f;
    float sum[4] = {0.f, 0.f, 0.f, 0.f};
#pragma unroll
    for (int nt = 0; nt < 13; ++nt)
#pragma unroll
      for (int reg = 0; reg < 4; ++reg) {
        float p = exp2f((S[nt][reg] - mx[reg]) * CEXP);
        S[nt][reg] = p;
        sum[reg] += p;
      }
#pragma unroll
    for (int off = 1; off < 16; off <<= 1)
#pragma unroll
      for (int reg = 0; reg < 4; ++reg) sum[reg] += __shfl_xor(sum[reg], off, 64);
    float inv[4];
#pragma unroll
    for (int reg = 0; reg < 4; ++reg) inv[reg] = __builtin_amdgcn_rcpf(sum[reg]);

    // PV: chunked P->LDS (wave-private; DS in-order per wave)
    f4_t o[4];
#pragma unroll
    for (int dt = 0; dt < 4; ++dt) o[dt] = (f4_t){0.f, 0.f, 0.f, 0.f};
    unsigned short* buf = Ps[wave];
#pragma unroll
    for (int kt = 0; kt < 7; ++kt) {
#pragma unroll
      for (int reg = 0; reg < 4; ++reg) {
        float p0 = S[kt * 2][reg];
        float p1 = (kt * 2 + 1 < 13) ? S[kt * 2 + 1][reg] : 0.f;
        unsigned int u = cvt_pk_bf16(p0, p1);
        buf[(quad * 4 + reg) * 40 + mfrag]      = (unsigned short)u;
        buf[(quad * 4 + reg) * 40 + 16 + mfrag] = (unsigned short)(u >> 16);
      }
      bf8_t pf = *(const bf8_t*)(buf + mfrag * 40 + quad * 8);
#pragma unroll
      for (int dt = 0; dt < 4; ++dt) {
        bf8_t vf = *(const bf8_t*)(Vt + (dt * 16 + mfrag) * 232 + kt * 32 + quad * 8);
        o[dt] = __builtin_amdgcn_mfma_f32_16x16x32_bf16(pf, vf, o[dt], 0, 0, 0);
      }
    }

    // msg store: lane holds o[dt][reg] = out[q=quad*4+reg][d=dt*16+mfrag]
#pragma unroll
    for (int dt = 0; dt < 4; dt += 2)
#pragma unroll
      for (int reg = 0; reg < 4; ++reg) {
        int q = m0 + quad * 4 + reg;
        unsigned int u = cvt_pk_bf16(o[dt][reg] * inv[reg], o[dt + 1][reg] * inv[reg]);
        if (q < 197) {
          size_t base = (size_t)e * 37824 + q * 192 + h * 64 + dt * 16 + mfrag;
          msgbuf[base]      = (unsigned short)u;
          msgbuf[base + 16] = (unsigned short)(u >> 16);
        }
      }
  }
}

// ---------------------------------------------------------------------------
// Per-dst aggregation, bf16x8 vectorized.  grid (256 dst, 4 chunks).
// ---------------------------------------------------------------------------
__global__ __launch_bounds__(256) void aggregate_kernel(
    const unsigned short* __restrict__ msgbuf, const int* __restrict__ edge,
    unsigned short* __restrict__ agg, int* __restrict__ cntg) {
  const int b = blockIdx.x, chunk = blockIdx.y;
  __shared__ int list[1024];
  __shared__ int lc;
  const int tid = threadIdx.x;
  if (tid == 0) lc = 0;
  __syncthreads();
  for (int e = tid; e < 1024; e += 256)
    if (edge[1024 + e] == b) { int p = atomicAdd(&lc, 1); list[p] = e; }
  __syncthreads();
  const int cnt = lc;
  if (chunk == 0 && tid == 0) cntg[b] = cnt;
  const int base = chunk * 9456;  // 37824 = 4*9456, 9456 = 1182*8
  for (int i8 = tid; i8 < 1182; i8 += 256) {
    int i = base + i8 * 8;
    float sum[8];
#pragma unroll
    for (int kk = 0; kk < 8; ++kk) sum[kk] = 0.f;
    for (int j = 0; j < cnt; ++j) {
      float4 t = *(const float4*)(msgbuf + (size_t)list[j] * 37824 + i);
      const unsigned short* u = (const unsigned short*)&t;
#pragma unroll
      for (int kk = 0; kk < 8; ++kk) sum[kk] += bf2f(u[kk]);
    }
    unsigned short o[8];
#pragma unroll
    for (int kk = 0; kk < 8; ++kk) o[kk] = f2bf(sum[kk]);
    *(float4*)(agg + (size_t)b * 37824 + i) = *(const float4*)o;
  }
}

// ---------------------------------------------------------------------------
extern "C" void kernel_launch(void* const* d_in, const int* in_sizes, int n_in,
                              void* d_out, int out_size, void* d_ws, size_t ws_size,
                              hipStream_t stream) {
  const float* x      = (const float*)d_in[0];
  const int*   edge   = (const int*)d_in[1];
  const float* n1g    = (const float*)d_in[2];
  const float* n1b    = (const float*)d_in[3];
  const float* qkv_w  = (const float*)d_in[4];
  const float* proj_w = (const float*)d_in[5];
  const float* proj_b = (const float*)d_in[6];
  const float* n2g    = (const float*)d_in[7];
  const float* n2b    = (const float*)d_in[8];
  const float* fc1_w  = (const float*)d_in[9];
  const float* fc1_b  = (const float*)d_in[10];
  const float* fc2_w  = (const float*)d_in[11];
  const float* fc2_b  = (const float*)d_in[12];
  float* out = (float*)d_out;

  char* ws = (char*)d_ws;
  unsigned short* msgbuf = (unsigned short*)ws;
  unsigned short* h1     = (unsigned short*)ws;                    // overlays msgbuf
  unsigned short* qk     = (unsigned short*)(ws + 77463552);
  unsigned short* xn     = (unsigned short*)(ws + 116195328);
  unsigned short* agg    = (unsigned short*)(ws + 135561216);
  unsigned short* vtg    = (unsigned short*)(ws + 154927104);
  unsigned short* wqkv   = (unsigned short*)(ws + 174587904);
  unsigned short* wproj  = (unsigned short*)(ws + 174809088);
  unsigned short* wfc1   = (unsigned short*)(ws + 174882816);
  unsigned short* wfc2   = (unsigned short*)(ws + 175177728);
  int*            cntg   = (int*)           (ws + 175472640);

  dim3 blk(256);
  wcvt_kernel<<<dim3(1728), blk, 0, stream>>>(qkv_w, proj_w, fc1_w, fc2_w, wqkv);

  ln_bf16_kernel<<<dim3(12608), blk, 0, stream>>>(x, n1g, n1b, xn);
  gemm_bf16<0, 1><<<dim3(394, 9), blk, 0, stream>>>(xn, wqkv, nullptr, nullptr, nullptr, qk, vtg, 384);
  attnA_kernel<<<dim3(1024, 3), dim3(512), 0, stream>>>(qk, vtg, edge, msgbuf);
  aggregate_kernel<<<dim3(256, 4), blk, 0, stream>>>(msgbuf, edge, agg, cntg);
  proj_ln_kernel<<<dim3(394), blk, 0, stream>>>(agg, wproj, proj_b, x, cntg, n2g, n2b, out, xn);
  gemm_bf16<2, 1><<<dim3(394, 12), blk, 0, stream>>>(xn, wfc1, fc1_b, nullptr, nullptr, h1, nullptr, 768);
  gemm_bf16<3, 4><<<dim3(394, 3), blk, 0, stream>>>(h1, wfc2, fc2_b, out, nullptr, out, nullptr, 192);
}

// Round 8
// 426.429 us; speedup vs baseline: 1.2769x; 1.0533x over previous
//
#include <hip/hip_runtime.h>
#include <hip/hip_bf16.h>
#include <cstddef>

// Bn=256, N=197, C=192, H=3, hd=64, E=1024, hid=768, M = Bn*N = 50432 = 394*128 = 788*64
//
// ws layout (bytes):
//   [0,          77463552)   : msgbuf bf16 [1024][197][192]
//   [77463552,  116195328)   : qk  bf16 [50432][384]   (Q cols 0..191, K cols 192..383)
//   [116195328, 135561216)   : xn  bf16 [50432][192]   (reused as x2n after proj+LN2 fusion)
//   [135561216, 154927104)   : agg bf16 [50432][192]
//   [154927104, 174587904)   : vt  bf16 [256][3][64][200]  (V transposed, t contiguous; cols 197..199 garbage)
//   [174587904, 175472640)   : bf16 weights, contiguous: wqkv|wproj|wfc1|wfc2
//   [175472640, 175473664)   : cnt int32[256]

typedef __attribute__((ext_vector_type(8))) short bf8_t;
typedef __attribute__((ext_vector_type(4))) float f4_t;

#define GLOBAL_AS __attribute__((address_space(1)))
#define LDS_AS    __attribute__((address_space(3)))

__device__ __forceinline__ float bf2f(unsigned short u) {
  union { unsigned int i; float f; } x; x.i = ((unsigned int)u) << 16; return x.f;
}
__device__ __forceinline__ unsigned short f2bf(float f) {
  unsigned int u = __builtin_bit_cast(unsigned int, f);
  u = (u + 0x7FFFu + ((u >> 16) & 1u)) >> 16;
  return (unsigned short)u;
}
// packed f32x2 -> bf16x2 (RTNE), single VALU op (no builtin on gfx950)
__device__ __forceinline__ unsigned int cvt_pk_bf16(float a, float b) {
  unsigned int r;
  asm("v_cvt_pk_bf16_f32 %0, %1, %2" : "=v"(r) : "v"(a), "v"(b));
  return r;
}
// async global->LDS, 16B per lane; LDS dest = base + lane*16 (linear), global src per-lane
__device__ __forceinline__ void gload16(const unsigned short* g, unsigned short* l) {
  __builtin_amdgcn_global_load_lds((const GLOBAL_AS unsigned int*)g,
                                   (LDS_AS unsigned int*)l, 16, 0, 0);
}

// ---------------------------------------------------------------------------
// All four weight matrices -> bf16, one launch (dst regions are contiguous).
// ---------------------------------------------------------------------------
__global__ __launch_bounds__(256) void wcvt_kernel(
    const float* __restrict__ qkvw, const float* __restrict__ projw,
    const float* __restrict__ fc1w, const float* __restrict__ fc2w,
    unsigned short* __restrict__ dst) {
  int i = blockIdx.x * 256 + threadIdx.x;
  float v;
  if (i < 110592)      v = qkvw[i];
  else if (i < 147456) v = projw[i - 110592];
  else if (i < 294912) v = fc1w[i - 147456];
  else                 v = fc2w[i - 294912];
  dst[i] = f2bf(v);
}

// ---------------------------------------------------------------------------
// LayerNorm(fp32 in) -> bf16 out.  One wave per row (C=192, 3 elems/lane).
// ---------------------------------------------------------------------------
__global__ __launch_bounds__(256) void ln_bf16_kernel(const float* __restrict__ X,
    const float* __restrict__ g, const float* __restrict__ b,
    unsigned short* __restrict__ Y) {
  int row = blockIdx.x * 4 + (threadIdx.x >> 6);
  int lane = threadIdx.x & 63;
  const float* xr = X + (size_t)row * 192;
  float v0 = xr[lane], v1 = xr[lane + 64], v2 = xr[lane + 128];
  float s = v0 + v1 + v2, ss = v0 * v0 + v1 * v1 + v2 * v2;
#pragma unroll
  for (int o = 32; o > 0; o >>= 1) { s += __shfl_xor(s, o, 64); ss += __shfl_xor(ss, o, 64); }
  float mean = s * (1.f / 192.f);
  float var = ss * (1.f / 192.f) - mean * mean;
  float r = rsqrtf(var + 1e-5f);
  unsigned short* yr = Y + (size_t)row * 192;
  yr[lane]       = f2bf((v0 - mean) * r * g[lane]       + b[lane]);
  yr[lane + 64]  = f2bf((v1 - mean) * r * g[lane + 64]  + b[lane + 64]);
  yr[lane + 128] = f2bf((v2 - mean) * r * g[lane + 128] + b[lane + 128]);
}

// ---------------------------------------------------------------------------
// bf16 MFMA GEMM: C = f( A @ W^T ), tile 128x64, 4 waves.
// Staging via global_load_lds width=16.  LDA=208 shorts.
// MODE 0: qkv -> qk bf16 (cols<384) + vt bf16 transposed (cols>=384)
// ---------------------------------------------------------------------------
template<int MODE, int NK>
__global__ __launch_bounds__(256) void gemm_bf16(
    const unsigned short* __restrict__ A, const unsigned short* __restrict__ W,
    const float* __restrict__ bias, const float* __restrict__ xres,
    const int* __restrict__ cntg, void* __restrict__ Cout,
    unsigned short* __restrict__ Cvt, int ldc) {
  constexpr int LDA = 208;                 // shorts; 26 16B-segments per row
  __shared__ unsigned short As[128 * LDA]; // 52 chunks of 1024B
  __shared__ unsigned short Ws[64 * LDA];  // 26 chunks of 1024B
  const int tid = threadIdx.x;
  const int m0 = blockIdx.x * 128, n0 = blockIdx.y * 64;
  const int wave = tid >> 6, lane = tid & 63;
  const int mfrag = lane & 15, quad = lane >> 4;
  const int K = NK * 192;

  f4_t acc[2][4];
#pragma unroll
  for (int i = 0; i < 2; ++i)
#pragma unroll
    for (int j = 0; j < 4; ++j) acc[i][j] = (f4_t){0.f, 0.f, 0.f, 0.f};

  for (int kc = 0; kc < NK; ++kc) {
    __syncthreads();
    for (int it = wave; it < 78; it += 4) {
      if (it < 52) {
        int idx = it * 64 + lane;
        int r = idx / 26, c = idx % 26;
        int c8 = min(c * 8, 184);
        gload16(A + (size_t)(m0 + r) * K + kc * 192 + c8, As + it * 512);
      } else {
        int idx = (it - 52) * 64 + lane;
        int r = idx / 26, c = idx % 26;
        int c8 = min(c * 8, 184);
        gload16(W + (size_t)(n0 + r) * K + kc * 192 + c8, Ws + (it - 52) * 512);
      }
    }
    __syncthreads();
#pragma unroll
    for (int ks = 0; ks < 6; ++ks) {
      bf8_t a0 = *(const bf8_t*)(As + (wave * 32 + mfrag) * LDA + ks * 32 + quad * 8);
      bf8_t a1 = *(const bf8_t*)(As + (wave * 32 + 16 + mfrag) * LDA + ks * 32 + quad * 8);
#pragma unroll
      for (int nt = 0; nt < 4; ++nt) {
        bf8_t bf = *(const bf8_t*)(Ws + (nt * 16 + mfrag) * LDA + ks * 32 + quad * 8);
        acc[0][nt] = __builtin_amdgcn_mfma_f32_16x16x32_bf16(a0, bf, acc[0][nt], 0, 0, 0);
        acc[1][nt] = __builtin_amdgcn_mfma_f32_16x16x32_bf16(a1, bf, acc[1][nt], 0, 0, 0);
      }
    }
  }

#pragma unroll
  for (int mt = 0; mt < 2; ++mt)
#pragma unroll
    for (int nt = 0; nt < 4; ++nt)
#pragma unroll
      for (int reg = 0; reg < 4; ++reg) {
        int row = m0 + wave * 32 + mt * 16 + quad * 4 + reg;
        int col = n0 + nt * 16 + mfrag;
        float v = acc[mt][nt][reg];
        if constexpr (MODE == 0) {
          if (col < 384) {
            ((unsigned short*)Cout)[(size_t)row * 384 + col] = f2bf(v);
          } else {
            int cc = col - 384, hh = cc >> 6, dd = cc & 63;
            int bb = row / 197, tt = row - bb * 197;
            Cvt[((size_t)(bb * 3 + hh) * 64 + dd) * 200 + tt] = f2bf(v);
          }
        }
      }
}

// ---------------------------------------------------------------------------
// Fused MLP: out += gelu(xn @ fc1^T + b1) @ fc2^T + b2, K-blocked over hid.
// Grid (788), 64 rows/block, 4 waves (16 rows each).  Per hid-chunk (64):
//   GEMM1 -> gelu -> bf16 into Hs (wave-private rows; DS in-order, no barrier
//   needed between own-row write and read) -> GEMM2 accumulates into
//   acc2[12] f4.  fc1/fc2 weight chunks time-share one LDS buffer WF
//   (disjoint live ranges, 4 barriers/chunk).  Eliminates the h1 bf16
//   [50432][768] intermediate (77 MB write + 77 MB read) and one launch.
// ---------------------------------------------------------------------------
__global__ __launch_bounds__(256) void mlp_kernel(
    const unsigned short* __restrict__ xn,    // [M][192]
    const unsigned short* __restrict__ wfc1,  // [768][192]
    const unsigned short* __restrict__ wfc2,  // [192][768]
    const float* __restrict__ b1, const float* __restrict__ b2,
    float* __restrict__ outF) {               // [M][192], in-place +=
  __shared__ unsigned short As[64 * 208];   // xn tile     (26,624 B)
  __shared__ unsigned short WF[13824];      // fc1 view [64][208] / fc2 view [192][72]
  __shared__ unsigned short Hs[64 * 72];    // gelu(h) chunk (9,216 B)
  const int tid = threadIdx.x;
  const int m0 = blockIdx.x * 64;
  const int wave = tid >> 6, lane = tid & 63;
  const int mfrag = lane & 15, quad = lane >> 4;

  // stage A once: 64 rows x 26 segs; it*512 + lane*8 == r*208 + c*8
  for (int it = wave; it < 26; it += 4) {
    int idx = it * 64 + lane;
    int r = idx / 26, c = idx % 26;
    int c8 = min(c * 8, 184);
    gload16(xn + (size_t)(m0 + r) * 192 + c8, As + it * 512);
  }

  f4_t acc2[12];
#pragma unroll
  for (int j = 0; j < 12; ++j) acc2[j] = (f4_t){0.f, 0.f, 0.f, 0.f};

  for (int hc = 0; hc < 12; ++hc) {
    __syncthreads();   // hc=0: nothing; hc>0: GEMM2 readers of WF done
    // stage fc1 chunk rows hc*64..+63 (K=192) into WF [64][208]
    for (int it = wave; it < 26; it += 4) {
      int idx = it * 64 + lane;
      int r = idx / 26, c = idx % 26;
      int c8 = min(c * 8, 184);
      gload16(wfc1 + (size_t)(hc * 64 + r) * 192 + c8, WF + it * 512);
    }
    __syncthreads();   // WF(fc1) ready; As ready too (hc=0)

    // GEMM1: 16 rows x 64 cols per wave
    f4_t acc1[4];
#pragma unroll
    for (int j = 0; j < 4; ++j) acc1[j] = (f4_t){0.f, 0.f, 0.f, 0.f};
#pragma unroll
    for (int ks = 0; ks < 6; ++ks) {
      bf8_t a0 = *(const bf8_t*)(As + (wave * 16 + mfrag) * 208 + ks * 32 + quad * 8);
#pragma unroll
      for (int nt = 0; nt < 4; ++nt) {
        bf8_t bf = *(const bf8_t*)(WF + (nt * 16 + mfrag) * 208 + ks * 32 + quad * 8);
        acc1[nt] = __builtin_amdgcn_mfma_f32_16x16x32_bf16(a0, bf, acc1[nt], 0, 0, 0);
      }
    }
    // gelu + bias -> bf16 -> Hs (own rows only)
#pragma unroll
    for (int nt = 0; nt < 4; ++nt) {
      float bb = b1[hc * 64 + nt * 16 + mfrag];
#pragma unroll
      for (int reg = 0; reg < 4; ++reg) {
        float v = acc1[nt][reg] + bb;
        v = 0.5f * v * (1.f + erff(v * 0.70710678118654752f));
        Hs[(wave * 16 + quad * 4 + reg) * 72 + nt * 16 + mfrag] = f2bf(v);
      }
    }

    __syncthreads();   // GEMM1 WF readers done before fc2 restage
    // stage fc2 chunk [192 rows][cols hc*64..+63] into WF [192][72]
    // (9 segs/row, seg 8 = pad duplicate; it*512 + lane*8 == r*72 + sg*8)
    for (int it = wave; it < 27; it += 4) {
      int idx = it * 64 + lane;
      int r = idx / 9, sg = idx % 9;
      int sg8 = min(sg * 8, 56);
      gload16(wfc2 + (size_t)r * 768 + hc * 64 + sg8, WF + it * 512);
    }
    __syncthreads();   // WF(fc2) ready

    // GEMM2: acc2 += Hc @ fc2_chunk^T   (A from Hs own rows, K=64)
#pragma unroll
    for (int ks = 0; ks < 2; ++ks) {
      bf8_t a0 = *(const bf8_t*)(Hs + (wave * 16 + mfrag) * 72 + ks * 32 + quad * 8);
#pragma unroll
      for (int nt = 0; nt < 12; ++nt) {
        bf8_t bf = *(const bf8_t*)(WF + (nt * 16 + mfrag) * 72 + ks * 32 + quad * 8);
        acc2[nt] = __builtin_amdgcn_mfma_f32_16x16x32_bf16(a0, bf, acc2[nt], 0, 0, 0);
      }
    }
  }

  // epilogue: out += acc2 + b2  (rows owned exclusively -> in-place safe)
#pragma unroll
  for (int nt = 0; nt < 12; ++nt) {
    float bb = b2[nt * 16 + mfrag];
#pragma unroll
    for (int reg = 0; reg < 4; ++reg) {
      int row = m0 + wave * 16 + quad * 4 + reg;
      int col = nt * 16 + mfrag;
      float v = acc2[nt][reg] + bb + outF[(size_t)row * 192 + col];
      outF[(size_t)row * 192 + col] = v;
    }
  }
}

// ---------------------------------------------------------------------------
// proj GEMM (128x192 per block, N looped in 3 chunks of 64) fused with the
// /cnt + bias + residual epilogue AND LayerNorm2.  Grid (394).
// ---------------------------------------------------------------------------
__global__ __launch_bounds__(256) void proj_ln_kernel(
    const unsigned short* __restrict__ A,   // agg bf16 [M][192]
    const unsigned short* __restrict__ W,   // wproj bf16 [192][192]
    const float* __restrict__ bias,         // proj_b
    const float* __restrict__ xres,         // x (input, f32)
    const int* __restrict__ cntg,
    const float* __restrict__ g2, const float* __restrict__ b2,
    float* __restrict__ outF,               // out f32 [M][192]
    unsigned short* __restrict__ xnout) {   // xn bf16 [M][192]
  constexpr int LDA = 208;
  __shared__ unsigned short As[128 * LDA];
  __shared__ unsigned short Ws[64 * LDA];
  const int tid = threadIdx.x;
  const int m0 = blockIdx.x * 128;
  const int wave = tid >> 6, lane = tid & 63;
  const int mfrag = lane & 15, quad = lane >> 4;

  f4_t acc[3][2][4];
#pragma unroll
  for (int nc = 0; nc < 3; ++nc)
#pragma unroll
    for (int i = 0; i < 2; ++i)
#pragma unroll
      for (int j = 0; j < 4; ++j) acc[nc][i][j] = (f4_t){0.f, 0.f, 0.f, 0.f};

  for (int it = wave; it < 52; it += 4) {
    int idx = it * 64 + lane;
    int r = idx / 26, c = idx % 26;
    int c8 = min(c * 8, 184);
    gload16(A + (size_t)(m0 + r) * 192 + c8, As + it * 512);
  }

  for (int nc = 0; nc < 3; ++nc) {
    if (nc > 0) __syncthreads();
    for (int it = wave; it < 26; it += 4) {
      int idx = it * 64 + lane;
      int r = idx / 26, c = idx % 26;
      int c8 = min(c * 8, 184);
      gload16(W + (size_t)(nc * 64 + r) * 192 + c8, Ws + it * 512);
    }
    __syncthreads();
#pragma unroll
    for (int ks = 0; ks < 6; ++ks) {
      bf8_t a0 = *(const bf8_t*)(As + (wave * 32 + mfrag) * LDA + ks * 32 + quad * 8);
      bf8_t a1 = *(const bf8_t*)(As + (wave * 32 + 16 + mfrag) * LDA + ks * 32 + quad * 8);
#pragma unroll
      for (int nt = 0; nt < 4; ++nt) {
        bf8_t bf = *(const bf8_t*)(Ws + (nt * 16 + mfrag) * LDA + ks * 32 + quad * 8);
        acc[nc][0][nt] = __builtin_amdgcn_mfma_f32_16x16x32_bf16(a0, bf, acc[nc][0][nt], 0, 0, 0);
        acc[nc][1][nt] = __builtin_amdgcn_mfma_f32_16x16x32_bf16(a1, bf, acc[nc][1][nt], 0, 0, 0);
      }
    }
  }

  float pb[12], pg[12], pbb[12];
#pragma unroll
  for (int nc = 0; nc < 3; ++nc)
#pragma unroll
    for (int nt = 0; nt < 4; ++nt) {
      int col = nc * 64 + nt * 16 + mfrag;
      pb[nc * 4 + nt] = bias[col];
      pg[nc * 4 + nt] = g2[col];
      pbb[nc * 4 + nt] = b2[col];
    }

#pragma unroll
  for (int mt = 0; mt < 2; ++mt)
#pragma unroll
    for (int reg = 0; reg < 4; ++reg) {
      const int row = m0 + wave * 32 + mt * 16 + quad * 4 + reg;
      const int cn = cntg[row / 197];
      const float rc = (cn > 0) ? 1.f / (float)cn : 0.f;
      float vv[12];
      float s = 0.f, ss = 0.f;
#pragma unroll
      for (int nc = 0; nc < 3; ++nc)
#pragma unroll
        for (int nt = 0; nt < 4; ++nt) {
          int col = nc * 64 + nt * 16 + mfrag;
          float v = (cn > 0) ? acc[nc][mt][nt][reg] * rc + pb[nc * 4 + nt] : 0.f;
          v += xres[(size_t)row * 192 + col];
          vv[nc * 4 + nt] = v;
          s += v;
          ss += v * v;
        }
#pragma unroll
      for (int off = 1; off < 16; off <<= 1) {
        s += __shfl_xor(s, off, 64);
        ss += __shfl_xor(ss, off, 64);
      }
      const float mean = s * (1.f / 192.f);
      const float var = ss * (1.f / 192.f) - mean * mean;
      const float r = rsqrtf(var + 1e-5f);
#pragma unroll
      for (int nc = 0; nc < 3; ++nc)
#pragma unroll
        for (int nt = 0; nt < 4; ++nt) {
          int col = nc * 64 + nt * 16 + mfrag;
          float v = vv[nc * 4 + nt];
          outF[(size_t)row * 192 + col] = v;
          xnout[(size_t)row * 192 + col] =
              f2bf((v - mean) * r * pg[nc * 4 + nt] + pbb[nc * 4 + nt]);
        }
    }
}

// ---------------------------------------------------------------------------
// MFMA attention (R1/R4-exact known-good).  One block per (edge e, head h);
// 512 threads / 8 waves.
// ---------------------------------------------------------------------------
__global__ __launch_bounds__(512) void attnA_kernel(
    const unsigned short* __restrict__ qk, const unsigned short* __restrict__ vtg,
    const int* __restrict__ edge, unsigned short* __restrict__ msgbuf) {
  const int e = blockIdx.x, h = blockIdx.y;
  const int s = edge[e], b = edge[1024 + e];
  __shared__ unsigned short Ks[208 * 72];
  __shared__ unsigned short Vt[64 * 232];
  __shared__ unsigned short Ps[8][640];   // [wave][16*40], single buffer (DS in-order per wave)
  const int tid = threadIdx.x;
  const int wave = tid >> 6, lane = tid & 63;
  const int mfrag = lane & 15, quad = lane >> 4;

  for (int i = tid; i < 197 * 8; i += 512) {
    int m = i >> 3, c8 = i & 7;
    *(float4*)(Ks + m * 72 + c8 * 8) =
        *(const float4*)(qk + (size_t)(s * 197 + m) * 384 + 192 + h * 64 + c8 * 8);
  }
  for (int i = tid; i < 64 * 25; i += 512) {
    int d = i / 25, c8 = i - d * 25;
    *(float4*)(Vt + d * 232 + c8 * 8) =
        *(const float4*)(vtg + ((size_t)(b * 3 + h) * 64 + d) * 200 + c8 * 8);
  }
  __syncthreads();
  for (int i = tid; i < 64 * 35; i += 512) {
    int d = i / 35, kk = 197 + (i - d * 35);
    Vt[d * 232 + kk] = 0;
  }
  __syncthreads();

  for (int st = wave; st < 13; st += 8) {
    const int m0 = st * 16;
    const size_t qrow = (size_t)(b * 197 + min(m0 + mfrag, 196)) * 384 + h * 64;
    bf8_t a0 = *(const bf8_t*)(qk + qrow + quad * 8);
    bf8_t a1 = *(const bf8_t*)(qk + qrow + 32 + quad * 8);

    f4_t S[13];
#pragma unroll
    for (int nt = 0; nt < 13; ++nt) {
      bf8_t k0 = *(const bf8_t*)(Ks + (nt * 16 + mfrag) * 72 + quad * 8);
      bf8_t k1 = *(const bf8_t*)(Ks + (nt * 16 + mfrag) * 72 + 32 + quad * 8);
      f4_t z = (f4_t){0.f, 0.f, 0.f, 0.f};
      z = __builtin_amdgcn_mfma_f32_16x16x32_bf16(a0, k0, z, 0, 0, 0);
      S[nt] = __builtin_amdgcn_mfma_f32_16x16x32_bf16(a1, k1, z, 0, 0, 0);
    }

#pragma unroll
    for (int reg = 0; reg < 4; ++reg)
      S[12][reg] = (mfrag < 5) ? S[12][reg] : -1e30f;

    float mx[4] = {-1e30f, -1e30f, -1e30f, -1e30f};
#pragma unroll
    for (int nt = 0; nt < 13; ++nt)
#pragma unroll
      for (int reg = 0; reg < 4; ++reg) mx[reg] = fmaxf(mx[reg], S[nt][reg]);
#pragma unroll
    for (int off = 1; off < 16; off <<= 1)
#pragma unroll
      for (int reg = 0; reg < 4; ++reg) mx[reg] = fmaxf(mx[reg], __shfl_xor(mx[reg], off, 64));

    constexpr float CEXP = 0.18033688011112042f;
    float sum[4] = {0.f, 0.f, 0.f, 0.f};
#pragma unroll
    for (int nt = 0; nt < 13; ++nt)
#pragma unroll
      for (int reg = 0; reg < 4; ++reg) {
        float p = exp2f((S[nt][reg] - mx[reg]) * CEXP);
        S[nt][reg] = p;
        sum[reg] += p;
      }
#pragma unroll
    for (int off = 1; off < 16; off <<= 1)
#pragma unroll
      for (int reg = 0; reg < 4; ++reg) sum[reg] += __shfl_xor(sum[reg], off, 64);
    float inv[4];
#pragma unroll
    for (int reg = 0; reg < 4; ++reg) inv[reg] = __builtin_amdgcn_rcpf(sum[reg]);

    f4_t o[4];
#pragma unroll
    for (int dt = 0; dt < 4; ++dt) o[dt] = (f4_t){0.f, 0.f, 0.f, 0.f};
    unsigned short* buf = Ps[wave];
#pragma unroll
    for (int kt = 0; kt < 7; ++kt) {
#pragma unroll
      for (int reg = 0; reg < 4; ++reg) {
        float p0 = S[kt * 2][reg];
        float p1 = (kt * 2 + 1 < 13) ? S[kt * 2 + 1][reg] : 0.f;
        unsigned int u = cvt_pk_bf16(p0, p1);
        buf[(quad * 4 + reg) * 40 + mfrag]      = (unsigned short)u;
        buf[(quad * 4 + reg) * 40 + 16 + mfrag] = (unsigned short)(u >> 16);
      }
      bf8_t pf = *(const bf8_t*)(buf + mfrag * 40 + quad * 8);
#pragma unroll
      for (int dt = 0; dt < 4; ++dt) {
        bf8_t vf = *(const bf8_t*)(Vt + (dt * 16 + mfrag) * 232 + kt * 32 + quad * 8);
        o[dt] = __builtin_amdgcn_mfma_f32_16x16x32_bf16(pf, vf, o[dt], 0, 0, 0);
      }
    }

#pragma unroll
    for (int dt = 0; dt < 4; dt += 2)
#pragma unroll
      for (int reg = 0; reg < 4; ++reg) {
        int q = m0 + quad * 4 + reg;
        unsigned int u = cvt_pk_bf16(o[dt][reg] * inv[reg], o[dt + 1][reg] * inv[reg]);
        if (q < 197) {
          size_t base = (size_t)e * 37824 + q * 192 + h * 64 + dt * 16 + mfrag;
          msgbuf[base]      = (unsigned short)u;
          msgbuf[base + 16] = (unsigned short)(u >> 16);
        }
      }
  }
}

// ---------------------------------------------------------------------------
// Per-dst aggregation, bf16x8 vectorized.  grid (256 dst, 4 chunks).
// ---------------------------------------------------------------------------
__global__ __launch_bounds__(256) void aggregate_kernel(
    const unsigned short* __restrict__ msgbuf, const int* __restrict__ edge,
    unsigned short* __restrict__ agg, int* __restrict__ cntg) {
  const int b = blockIdx.x, chunk = blockIdx.y;
  __shared__ int list[1024];
  __shared__ int lc;
  const int tid = threadIdx.x;
  if (tid == 0) lc = 0;
  __syncthreads();
  for (int e = tid; e < 1024; e += 256)
    if (edge[1024 + e] == b) { int p = atomicAdd(&lc, 1); list[p] = e; }
  __syncthreads();
  const int cnt = lc;
  if (chunk == 0 && tid == 0) cntg[b] = cnt;
  const int base = chunk * 9456;  // 37824 = 4*9456, 9456 = 1182*8
  for (int i8 = tid; i8 < 1182; i8 += 256) {
    int i = base + i8 * 8;
    float sum[8];
#pragma unroll
    for (int kk = 0; kk < 8; ++kk) sum[kk] = 0.f;
    for (int j = 0; j < cnt; ++j) {
      float4 t = *(const float4*)(msgbuf + (size_t)list[j] * 37824 + i);
      const unsigned short* u = (const unsigned short*)&t;
#pragma unroll
      for (int kk = 0; kk < 8; ++kk) sum[kk] += bf2f(u[kk]);
    }
    unsigned short o[8];
#pragma unroll
    for (int kk = 0; kk < 8; ++kk) o[kk] = f2bf(sum[kk]);
    *(float4*)(agg + (size_t)b * 37824 + i) = *(const float4*)o;
  }
}

// ---------------------------------------------------------------------------
extern "C" void kernel_launch(void* const* d_in, const int* in_sizes, int n_in,
                              void* d_out, int out_size, void* d_ws, size_t ws_size,
                              hipStream_t stream) {
  const float* x      = (const float*)d_in[0];
  const int*   edge   = (const int*)d_in[1];
  const float* n1g    = (const float*)d_in[2];
  const float* n1b    = (const float*)d_in[3];
  const float* qkv_w  = (const float*)d_in[4];
  const float* proj_w = (const float*)d_in[5];
  const float* proj_b = (const float*)d_in[6];
  const float* n2g    = (const float*)d_in[7];
  const float* n2b    = (const float*)d_in[8];
  const float* fc1_w  = (const float*)d_in[9];
  const float* fc1_b  = (const float*)d_in[10];
  const float* fc2_w  = (const float*)d_in[11];
  const float* fc2_b  = (const float*)d_in[12];
  float* out = (float*)d_out;

  char* ws = (char*)d_ws;
  unsigned short* msgbuf = (unsigned short*)ws;
  unsigned short* qk     = (unsigned short*)(ws + 77463552);
  unsigned short* xn     = (unsigned short*)(ws + 116195328);
  unsigned short* agg    = (unsigned short*)(ws + 135561216);
  unsigned short* vtg    = (unsigned short*)(ws + 154927104);
  unsigned short* wqkv   = (unsigned short*)(ws + 174587904);
  unsigned short* wproj  = (unsigned short*)(ws + 174809088);
  unsigned short* wfc1   = (unsigned short*)(ws + 174882816);
  unsigned short* wfc2   = (unsigned short*)(ws + 175177728);
  int*            cntg   = (int*)           (ws + 175472640);

  dim3 blk(256);
  wcvt_kernel<<<dim3(1728), blk, 0, stream>>>(qkv_w, proj_w, fc1_w, fc2_w, wqkv);

  ln_bf16_kernel<<<dim3(12608), blk, 0, stream>>>(x, n1g, n1b, xn);
  gemm_bf16<0, 1><<<dim3(394, 9), blk, 0, stream>>>(xn, wqkv, nullptr, nullptr, nullptr, qk, vtg, 384);
  attnA_kernel<<<dim3(1024, 3), dim3(512), 0, stream>>>(qk, vtg, edge, msgbuf);
  aggregate_kernel<<<dim3(256, 4), blk, 0, stream>>>(msgbuf, edge, agg, cntg);
  proj_ln_kernel<<<dim3(394), blk, 0, stream>>>(agg, wproj, proj_b, x, cntg, n2g, n2b, out, xn);
  mlp_kernel<<<dim3(788), blk, 0, stream>>>(xn, wfc1, wfc2, fc1_b, fc2_b, out);
}